// Round 4
// baseline (122.533 us; speedup 1.0000x reference)
//
#include <hip/hip_runtime.h>
#include <hip/hip_bf16.h>

#define B_ 32
#define T_ 256
#define NIN_ 128
#define H_ 32
#define NOUT_ 128
#define R_ (B_ * T_)   // 8192 rows

#define C2L2E 2.88539008177792681472f   // 2*log2(e)
#define L2E   1.44269504088896341f
#define LN2   0.69314718055994531f

__device__ __forceinline__ float rfl(float x) {
    return __uint_as_float(__builtin_amdgcn_readfirstlane(__float_as_uint(x)));
}

// sigmoid core: rcp(exp2(o*2log2e + hpre) + 1);  tanh(hi+o) = 1 - 2*sig
__device__ __forceinline__ float sig_core(float o, float hpre) {
    float ex = __builtin_amdgcn_exp2f(fmaf(o, C2L2E, hpre));
    return __builtin_amdgcn_rcpf(ex + 1.0f);
}

// ---------------------------------------------------------------------------
// Kernel 1: per block = 4 rows x 32 h (128 threads, 2 waves).
//   y = x @ W_in^T + b_in  (stage in LDS) ; h = y @ W_h^T ; o = y @ W_o^T
// r-groups never cross waves -> no __syncthreads needed (wave-synchronous LDS).
// ---------------------------------------------------------------------------
__global__ void __launch_bounds__(128) k_yho(
        const float* __restrict__ x,
        const float* __restrict__ W_in,
        const float* __restrict__ b_in,
        const float* __restrict__ W_h,
        const float* __restrict__ W_o,
        float* __restrict__ y,
        float* __restrict__ h,
        float* __restrict__ o) {
    __shared__ float ys[4][H_];
    const int t   = threadIdx.x;
    const int r   = t >> 5;              // local row 0..3
    const int hh  = t & 31;
    const int row = blockIdx.x * 4 + r;

    {
        const float4* x4 = reinterpret_cast<const float4*>(x + row * NIN_);
        const float4* w4 = reinterpret_cast<const float4*>(W_in + hh * NIN_);
        float a0 = b_in[hh], a1 = 0.f;
        #pragma unroll
        for (int k = 0; k < NIN_ / 8; ++k) {
            float4 xv0 = x4[2 * k],     wv0 = w4[2 * k];
            float4 xv1 = x4[2 * k + 1], wv1 = w4[2 * k + 1];
            a0 += xv0.x * wv0.x + xv0.y * wv0.y + xv0.z * wv0.z + xv0.w * wv0.w;
            a1 += xv1.x * wv1.x + xv1.y * wv1.y + xv1.z * wv1.z + xv1.w * wv1.w;
        }
        float acc = a0 + a1;
        ys[r][hh] = acc;
        y[row * H_ + hh] = acc;
    }
    // same-wave LDS produce->consume: compiler inserts lgkmcnt waits
    {
        const float4* y4  = reinterpret_cast<const float4*>(&ys[r][0]);
        const float4* wh4 = reinterpret_cast<const float4*>(W_h + hh * H_);
        const float4* wo4 = reinterpret_cast<const float4*>(W_o + hh * H_);
        float ah0 = 0.f, ah1 = 0.f, ao0 = 0.f, ao1 = 0.f;
        #pragma unroll
        for (int k = 0; k < H_ / 8; ++k) {
            float4 yv0 = y4[2 * k],     hv0 = wh4[2 * k],     ov0 = wo4[2 * k];
            float4 yv1 = y4[2 * k + 1], hv1 = wh4[2 * k + 1], ov1 = wo4[2 * k + 1];
            ah0 += yv0.x * hv0.x + yv0.y * hv0.y + yv0.z * hv0.z + yv0.w * hv0.w;
            ah1 += yv1.x * hv1.x + yv1.y * hv1.y + yv1.z * hv1.z + yv1.w * hv1.w;
            ao0 += yv0.x * ov0.x + yv0.y * ov0.y + yv0.z * ov0.z + yv0.w * ov0.w;
            ao1 += yv1.x * ov1.x + yv1.y * ov1.y + yv1.z * ov1.z + yv1.w * ov1.w;
        }
        h[row * H_ + hh] = ah0 + ah1;
        o[row * H_ + hh] = ao0 + ao1;
    }
}

// ---------------------------------------------------------------------------
// Kernel 2: ONE WAVE PER QUERY i. 4 waves/block, zero __syncthreads.
//   lane computes e_j for j = lane + 64q (q=0..3), softmax = wave shfl reduce,
//   att -> per-wave LDS slice (wave-synchronous), context half-split,
//   output projection 2 channels/lane.
// ---------------------------------------------------------------------------
__global__ void __launch_bounds__(256, 8) k_att(
        const float* __restrict__ y,
        const float* __restrict__ h,
        const float* __restrict__ o,
        const float* __restrict__ V,
        const float* __restrict__ W_out,
        const float* __restrict__ b_out,
        float* __restrict__ out) {
    __shared__ float att_lds[4][T_];
    __shared__ float ctx_lds[4][H_];

    const int t    = threadIdx.x;
    const int w    = __builtin_amdgcn_readfirstlane(t >> 6);  // wave 0..3
    const int lane = t & 63;
    const int iu   = blockIdx.x * 4 + w;      // global i-unit
    const int bb   = iu >> 8;
    const int ii   = iu & 255;
    (void)ii;

    // ---- wave-uniform scalars: hs[k] = h_i[k]*2log2e, w2[k] = -2V[k] ----
    const float* hrow = h + iu * H_;
    float hs[H_], w2[H_];
    float vsum = 0.f;
    #pragma unroll
    for (int k = 0; k < H_; ++k) {
        hs[k] = rfl(hrow[k] * C2L2E);
        float vk = V[k];
        w2[k] = rfl(vk * -2.0f);
        vsum += vk;
    }
    vsum = rfl(vsum);

    const float* obase = o + (bb * T_) * H_;

    // ---- e for 4 j's per lane ----
    float e0, e1, e2, e3;
    {
        float ee[4];
        #pragma unroll
        for (int q = 0; q < 4; ++q) {
            const int j = lane + 64 * q;
            const float4* o4 = reinterpret_cast<const float4*>(obase + j * H_);
            float4 ov[8];
            #pragma unroll
            for (int p = 0; p < 8; ++p) ov[p] = o4[p];
            float a0 = 0.f, a1 = 0.f, a2 = 0.f, a3 = 0.f;
            #pragma unroll
            for (int p = 0; p < 8; ++p) {
                a0 = fmaf(w2[4 * p + 0], sig_core(ov[p].x, hs[4 * p + 0]), a0);
                a1 = fmaf(w2[4 * p + 1], sig_core(ov[p].y, hs[4 * p + 1]), a1);
                a2 = fmaf(w2[4 * p + 2], sig_core(ov[p].z, hs[4 * p + 2]), a2);
                a3 = fmaf(w2[4 * p + 3], sig_core(ov[p].w, hs[4 * p + 3]), a3);
            }
            ee[q] = ((a0 + a1) + (a2 + a3)) + vsum;
            // keep q's from being merged into one giant load cluster
            __builtin_amdgcn_sched_barrier(0);
        }
        e0 = ee[0]; e1 = ee[1]; e2 = ee[2]; e3 = ee[3];
    }

    // ---- wave-local softmax (no barriers) ----
    float m = fmaxf(fmaxf(e0, e1), fmaxf(e2, e3));
    #pragma unroll
    for (int off = 1; off < 64; off <<= 1)
        m = fmaxf(m, __shfl_xor(m, off));

    float s = __builtin_amdgcn_exp2f((e0 - m) * L2E)
            + __builtin_amdgcn_exp2f((e1 - m) * L2E)
            + __builtin_amdgcn_exp2f((e2 - m) * L2E)
            + __builtin_amdgcn_exp2f((e3 - m) * L2E);
    #pragma unroll
    for (int off = 1; off < 64; off <<= 1)
        s += __shfl_xor(s, off);
    const float lse = m + __builtin_amdgcn_logf(s) * LN2;

    att_lds[w][lane]       = e0 - lse;
    att_lds[w][lane + 64]  = e1 - lse;
    att_lds[w][lane + 128] = e2 - lse;
    att_lds[w][lane + 192] = e3 - lse;
    // same-wave LDS: compiler orders via lgkmcnt, no barrier needed

    // ---- context: ctx[hh] = sum_j att[j]*y[j][hh], half-split over lanes ----
    const int   hh   = lane & 31;
    const int   half = lane >> 5;
    const float* ybase = y + (bb * T_) * H_ + half * 128 * H_;
    const float* attw  = &att_lds[w][half * 128];
    float c0 = 0.f, c1 = 0.f, c2 = 0.f, c3 = 0.f;
    #pragma unroll
    for (int n = 0; n < 32; ++n) {
        float4 a4 = *reinterpret_cast<const float4*>(attw + 4 * n);
        c0 = fmaf(a4.x, ybase[(4 * n + 0) * H_ + hh], c0);
        c1 = fmaf(a4.y, ybase[(4 * n + 1) * H_ + hh], c1);
        c2 = fmaf(a4.z, ybase[(4 * n + 2) * H_ + hh], c2);
        c3 = fmaf(a4.w, ybase[(4 * n + 3) * H_ + hh], c3);
    }
    float cacc = (c0 + c1) + (c2 + c3);
    cacc += __shfl_xor(cacc, 32);            // combine halves
    if (half == 0) ctx_lds[w][hh] = cacc;

    // ---- output projection: 2 channels per lane ----
    float4 cv[8];
    #pragma unroll
    for (int p = 0; p < 8; ++p)
        cv[p] = *reinterpret_cast<const float4*>(&ctx_lds[w][4 * p]);

    #pragma unroll
    for (int ho = 0; ho < 2; ++ho) {
        const int oc = lane + 64 * ho;
        const float4* w4 = reinterpret_cast<const float4*>(W_out + oc * H_);
        float a0 = b_out[oc], a1 = 0.f, a2 = 0.f, a3 = 0.f;
        #pragma unroll
        for (int p = 0; p < 8; p += 4) {
            float4 wv0 = w4[p + 0], wv1 = w4[p + 1], wv2 = w4[p + 2], wv3 = w4[p + 3];
            a0 += wv0.x * cv[p + 0].x + wv0.y * cv[p + 0].y + wv0.z * cv[p + 0].z + wv0.w * cv[p + 0].w;
            a1 += wv1.x * cv[p + 1].x + wv1.y * cv[p + 1].y + wv1.z * cv[p + 1].z + wv1.w * cv[p + 1].w;
            a2 += wv2.x * cv[p + 2].x + wv2.y * cv[p + 2].y + wv2.z * cv[p + 2].z + wv2.w * cv[p + 2].w;
            a3 += wv3.x * cv[p + 3].x + wv3.y * cv[p + 3].y + wv3.z * cv[p + 3].z + wv3.w * cv[p + 3].w;
        }
        out[iu * NOUT_ + oc] = (a0 + a1) + (a2 + a3);
    }
}

// ---------------------------------------------------------------------------
extern "C" void kernel_launch(void* const* d_in, const int* in_sizes, int n_in,
                              void* d_out, int out_size, void* d_ws, size_t ws_size,
                              hipStream_t stream) {
    const float* x     = (const float*)d_in[0];
    const float* W_in  = (const float*)d_in[1];
    const float* b_in  = (const float*)d_in[2];
    const float* W_h   = (const float*)d_in[3];
    const float* W_o   = (const float*)d_in[4];
    const float* V     = (const float*)d_in[5];
    const float* W_out = (const float*)d_in[6];
    const float* b_out = (const float*)d_in[7];
    float* out = (float*)d_out;

    // workspace layout: y | h | o  (each R_*H_ floats = 1 MB)
    float* y = (float*)d_ws;
    float* h = y + R_ * H_;
    float* o = h + R_ * H_;

    k_yho<<<R_ / 4, 128, 0, stream>>>(x, W_in, b_in, W_h, W_o, y, h, o);
    k_att<<<R_ / 4, 256, 0, stream>>>(y, h, o, V, W_out, b_out, out);
}

// Round 5
// 84.983 us; speedup vs baseline: 1.4418x; 1.4418x over previous
//
#include <hip/hip_runtime.h>
#include <hip/hip_bf16.h>

#define B_ 32
#define T_ 256
#define NIN_ 128
#define H_ 32
#define NOUT_ 128
#define R_ (B_ * T_)   // 8192 rows

#define C2L2E 2.88539008177792681472f   // 2*log2(e)
#define L2E   1.44269504088896341f
#define LN2   0.69314718055994531f

__device__ __forceinline__ float rfl(float x) {
    return __uint_as_float(__builtin_amdgcn_readfirstlane(__float_as_uint(x)));
}

// sigmoid core: rcp(exp2(o*2log2e + hpre) + 1);  tanh(hi+o) = 1 - 2*sig
__device__ __forceinline__ float sig_core(float o, float hpre) {
    float ex = __builtin_amdgcn_exp2f(fmaf(o, C2L2E, hpre));
    return __builtin_amdgcn_rcpf(ex + 1.0f);
}

// ---------------------------------------------------------------------------
// Kernel 1: per block = 4 rows x 32 h (128 threads, 2 waves).
//   y = x @ W_in^T + b_in  (stage in LDS) ; h = y @ W_h^T ; o = y @ W_o^T
// r-groups never cross waves -> no __syncthreads needed (wave-synchronous LDS).
// ---------------------------------------------------------------------------
__global__ void __launch_bounds__(128) k_yho(
        const float* __restrict__ x,
        const float* __restrict__ W_in,
        const float* __restrict__ b_in,
        const float* __restrict__ W_h,
        const float* __restrict__ W_o,
        float* __restrict__ y,
        float* __restrict__ h,
        float* __restrict__ o) {
    __shared__ float ys[4][H_];
    const int t   = threadIdx.x;
    const int r   = t >> 5;              // local row 0..3
    const int hh  = t & 31;
    const int row = blockIdx.x * 4 + r;

    {
        const float4* x4 = reinterpret_cast<const float4*>(x + row * NIN_);
        const float4* w4 = reinterpret_cast<const float4*>(W_in + hh * NIN_);
        float a0 = b_in[hh], a1 = 0.f;
        #pragma unroll
        for (int k = 0; k < NIN_ / 8; ++k) {
            float4 xv0 = x4[2 * k],     wv0 = w4[2 * k];
            float4 xv1 = x4[2 * k + 1], wv1 = w4[2 * k + 1];
            a0 += xv0.x * wv0.x + xv0.y * wv0.y + xv0.z * wv0.z + xv0.w * wv0.w;
            a1 += xv1.x * wv1.x + xv1.y * wv1.y + xv1.z * wv1.z + xv1.w * wv1.w;
        }
        float acc = a0 + a1;
        ys[r][hh] = acc;
        y[row * H_ + hh] = acc;
    }
    // same-wave LDS produce->consume: compiler inserts lgkmcnt waits
    {
        const float4* y4  = reinterpret_cast<const float4*>(&ys[r][0]);
        const float4* wh4 = reinterpret_cast<const float4*>(W_h + hh * H_);
        const float4* wo4 = reinterpret_cast<const float4*>(W_o + hh * H_);
        float ah0 = 0.f, ah1 = 0.f, ao0 = 0.f, ao1 = 0.f;
        #pragma unroll
        for (int k = 0; k < H_ / 8; ++k) {
            float4 yv0 = y4[2 * k],     hv0 = wh4[2 * k],     ov0 = wo4[2 * k];
            float4 yv1 = y4[2 * k + 1], hv1 = wh4[2 * k + 1], ov1 = wo4[2 * k + 1];
            ah0 += yv0.x * hv0.x + yv0.y * hv0.y + yv0.z * hv0.z + yv0.w * hv0.w;
            ah1 += yv1.x * hv1.x + yv1.y * hv1.y + yv1.z * hv1.z + yv1.w * hv1.w;
            ao0 += yv0.x * ov0.x + yv0.y * ov0.y + yv0.z * ov0.z + yv0.w * ov0.w;
            ao1 += yv1.x * ov1.x + yv1.y * ov1.y + yv1.z * ov1.z + yv1.w * ov1.w;
        }
        h[row * H_ + hh] = ah0 + ah1;
        o[row * H_ + hh] = ao0 + ao1;
    }
}

// ---------------------------------------------------------------------------
// Kernel 2: ONE WAVE PER QUERY i. 4 waves/block, zero __syncthreads.
//   lane computes e_j for j = lane + 64q (q=0..3), softmax = wave shfl reduce,
//   att -> per-wave LDS slice (wave-synchronous), context half-split,
//   output projection 2 channels/lane.
// NOTE: no min-waves launch_bounds — round 4 showed (256,8) forces the
// SGPR budget under the 64 wave-uniform scalars and demotes hs/w2 to
// per-thread scratch (FETCH 9->120MB, WRITE 4->175MB). Plain (256) fits
// them in ~96 SGPRs (round 3 evidence).
// ---------------------------------------------------------------------------
__global__ void __launch_bounds__(256) k_att(
        const float* __restrict__ y,
        const float* __restrict__ h,
        const float* __restrict__ o,
        const float* __restrict__ V,
        const float* __restrict__ W_out,
        const float* __restrict__ b_out,
        float* __restrict__ out) {
    __shared__ float att_lds[4][T_];
    __shared__ float ctx_lds[4][H_];

    const int t    = threadIdx.x;
    const int w    = __builtin_amdgcn_readfirstlane(t >> 6);  // wave 0..3
    const int lane = t & 63;
    const int iu   = blockIdx.x * 4 + w;      // global i-unit
    const int bb   = iu >> 8;

    // ---- wave-uniform scalars: hs[k] = h_i[k]*2log2e, w2[k] = -2V[k] ----
    const float* hrow = h + iu * H_;
    float hs[H_], w2[H_];
    float vsum = 0.f;
    #pragma unroll
    for (int k = 0; k < H_; ++k) {
        hs[k] = rfl(hrow[k] * C2L2E);
        float vk = V[k];
        w2[k] = rfl(vk * -2.0f);
        vsum += vk;
    }
    vsum = rfl(vsum);

    const float* obase = o + (bb * T_) * H_;

    // ---- e for 4 j's per lane ----
    float e0, e1, e2, e3;
    {
        float ee[4];
        #pragma unroll
        for (int q = 0; q < 4; ++q) {
            const int j = lane + 64 * q;
            const float4* o4 = reinterpret_cast<const float4*>(obase + j * H_);
            float4 ov[8];
            #pragma unroll
            for (int p = 0; p < 8; ++p) ov[p] = o4[p];
            float a0 = 0.f, a1 = 0.f, a2 = 0.f, a3 = 0.f;
            #pragma unroll
            for (int p = 0; p < 8; ++p) {
                a0 = fmaf(w2[4 * p + 0], sig_core(ov[p].x, hs[4 * p + 0]), a0);
                a1 = fmaf(w2[4 * p + 1], sig_core(ov[p].y, hs[4 * p + 1]), a1);
                a2 = fmaf(w2[4 * p + 2], sig_core(ov[p].z, hs[4 * p + 2]), a2);
                a3 = fmaf(w2[4 * p + 3], sig_core(ov[p].w, hs[4 * p + 3]), a3);
            }
            ee[q] = ((a0 + a1) + (a2 + a3)) + vsum;
        }
        e0 = ee[0]; e1 = ee[1]; e2 = ee[2]; e3 = ee[3];
    }

    // ---- wave-local softmax (no barriers) ----
    float m = fmaxf(fmaxf(e0, e1), fmaxf(e2, e3));
    #pragma unroll
    for (int off = 1; off < 64; off <<= 1)
        m = fmaxf(m, __shfl_xor(m, off));

    float s = __builtin_amdgcn_exp2f((e0 - m) * L2E)
            + __builtin_amdgcn_exp2f((e1 - m) * L2E)
            + __builtin_amdgcn_exp2f((e2 - m) * L2E)
            + __builtin_amdgcn_exp2f((e3 - m) * L2E);
    #pragma unroll
    for (int off = 1; off < 64; off <<= 1)
        s += __shfl_xor(s, off);
    const float lse = m + __builtin_amdgcn_logf(s) * LN2;

    att_lds[w][lane]       = e0 - lse;
    att_lds[w][lane + 64]  = e1 - lse;
    att_lds[w][lane + 128] = e2 - lse;
    att_lds[w][lane + 192] = e3 - lse;
    // same-wave LDS: compiler orders via lgkmcnt, no barrier needed

    // ---- context: ctx[hh] = sum_j att[j]*y[j][hh], half-split over lanes ----
    const int   hh   = lane & 31;
    const int   half = lane >> 5;
    const float* ybase = y + (bb * T_) * H_ + half * 128 * H_;
    const float* attw  = &att_lds[w][half * 128];
    float c0 = 0.f, c1 = 0.f, c2 = 0.f, c3 = 0.f;
    #pragma unroll
    for (int n = 0; n < 32; ++n) {
        float4 a4 = *reinterpret_cast<const float4*>(attw + 4 * n);
        c0 = fmaf(a4.x, ybase[(4 * n + 0) * H_ + hh], c0);
        c1 = fmaf(a4.y, ybase[(4 * n + 1) * H_ + hh], c1);
        c2 = fmaf(a4.z, ybase[(4 * n + 2) * H_ + hh], c2);
        c3 = fmaf(a4.w, ybase[(4 * n + 3) * H_ + hh], c3);
    }
    float cacc = (c0 + c1) + (c2 + c3);
    cacc += __shfl_xor(cacc, 32);            // combine halves
    if (half == 0) ctx_lds[w][hh] = cacc;

    // ---- output projection: 2 channels per lane ----
    float4 cv[8];
    #pragma unroll
    for (int p = 0; p < 8; ++p)
        cv[p] = *reinterpret_cast<const float4*>(&ctx_lds[w][4 * p]);

    #pragma unroll
    for (int ho = 0; ho < 2; ++ho) {
        const int oc = lane + 64 * ho;
        const float4* w4 = reinterpret_cast<const float4*>(W_out + oc * H_);
        float a0 = b_out[oc], a1 = 0.f, a2 = 0.f, a3 = 0.f;
        #pragma unroll
        for (int p = 0; p < 8; p += 4) {
            float4 wv0 = w4[p + 0], wv1 = w4[p + 1], wv2 = w4[p + 2], wv3 = w4[p + 3];
            a0 += wv0.x * cv[p + 0].x + wv0.y * cv[p + 0].y + wv0.z * cv[p + 0].z + wv0.w * cv[p + 0].w;
            a1 += wv1.x * cv[p + 1].x + wv1.y * cv[p + 1].y + wv1.z * cv[p + 1].z + wv1.w * cv[p + 1].w;
            a2 += wv2.x * cv[p + 2].x + wv2.y * cv[p + 2].y + wv2.z * cv[p + 2].z + wv2.w * cv[p + 2].w;
            a3 += wv3.x * cv[p + 3].x + wv3.y * cv[p + 3].y + wv3.z * cv[p + 3].z + wv3.w * cv[p + 3].w;
        }
        out[iu * NOUT_ + oc] = (a0 + a1) + (a2 + a3);
    }
}

// ---------------------------------------------------------------------------
extern "C" void kernel_launch(void* const* d_in, const int* in_sizes, int n_in,
                              void* d_out, int out_size, void* d_ws, size_t ws_size,
                              hipStream_t stream) {
    const float* x     = (const float*)d_in[0];
    const float* W_in  = (const float*)d_in[1];
    const float* b_in  = (const float*)d_in[2];
    const float* W_h   = (const float*)d_in[3];
    const float* W_o   = (const float*)d_in[4];
    const float* V     = (const float*)d_in[5];
    const float* W_out = (const float*)d_in[6];
    const float* b_out = (const float*)d_in[7];
    float* out = (float*)d_out;

    // workspace layout: y | h | o  (each R_*H_ floats = 1 MB)
    float* y = (float*)d_ws;
    float* h = y + R_ * H_;
    float* o = h + R_ * H_;

    k_yho<<<R_ / 4, 128, 0, stream>>>(x, W_in, b_in, W_h, W_o, y, h, o);
    k_att<<<R_ / 4, 256, 0, stream>>>(y, h, o, V, W_out, b_out, out);
}

// Round 6
// 63.785 us; speedup vs baseline: 1.9210x; 1.3323x over previous
//
#include <hip/hip_runtime.h>
#include <hip/hip_bf16.h>

#define B_ 32
#define T_ 256
#define NIN_ 128
#define H_ 32
#define NOUT_ 128
#define R_ (B_ * T_)   // 8192 rows

#define C2L2E 2.88539008177792681472f   // 2*log2(e)
#define L2E   1.44269504088896341f
#define LN2   0.69314718055994531f

__device__ __forceinline__ float rfl(float x) {
    return __uint_as_float(__builtin_amdgcn_readfirstlane(__float_as_uint(x)));
}

// sigmoid core: rcp(exp2(o*2log2e + hpre) + 1);  tanh(hi+o) = 1 - 2*sig
__device__ __forceinline__ float sig_core(float o, float hpre) {
    float ex = __builtin_amdgcn_exp2f(fmaf(o, C2L2E, hpre));
    return __builtin_amdgcn_rcpf(ex + 1.0f);
}

// ---------------------------------------------------------------------------
// Kernel 1: y[row][h] = dot(x[row,:], W_in[h,:]) + b_in[h]
// ---------------------------------------------------------------------------
__global__ void __launch_bounds__(256) k_y(
        const float* __restrict__ x,
        const float* __restrict__ W_in,
        const float* __restrict__ b_in,
        float* __restrict__ y) {
    int idx = blockIdx.x * blockDim.x + threadIdx.x;
    int row = idx >> 5;
    int hh  = idx & 31;
    const float4* x4 = reinterpret_cast<const float4*>(x + row * NIN_);
    const float4* w4 = reinterpret_cast<const float4*>(W_in + hh * NIN_);
    float a0 = b_in[hh], a1 = 0.f;
    #pragma unroll
    for (int k = 0; k < NIN_ / 8; ++k) {
        float4 xv0 = x4[2 * k],     wv0 = w4[2 * k];
        float4 xv1 = x4[2 * k + 1], wv1 = w4[2 * k + 1];
        a0 += xv0.x * wv0.x + xv0.y * wv0.y + xv0.z * wv0.z + xv0.w * wv0.w;
        a1 += xv1.x * wv1.x + xv1.y * wv1.y + xv1.z * wv1.z + xv1.w * wv1.w;
    }
    y[idx] = a0 + a1;
}

// ---------------------------------------------------------------------------
// Kernel 2: h = y @ W_h^T ; o = y @ W_o^T
// ---------------------------------------------------------------------------
__global__ void __launch_bounds__(256) k_ho(
        const float* __restrict__ y,
        const float* __restrict__ W_h,
        const float* __restrict__ W_o,
        float* __restrict__ h,
        float* __restrict__ o) {
    int idx = blockIdx.x * blockDim.x + threadIdx.x;
    int row = idx >> 5;
    int g   = idx & 31;
    const float4* y4  = reinterpret_cast<const float4*>(y + row * H_);
    const float4* wh4 = reinterpret_cast<const float4*>(W_h + g * H_);
    const float4* wo4 = reinterpret_cast<const float4*>(W_o + g * H_);
    float ah0 = 0.f, ah1 = 0.f, ao0 = 0.f, ao1 = 0.f;
    #pragma unroll
    for (int k = 0; k < H_ / 8; ++k) {
        float4 yv0 = y4[2 * k],     hv0 = wh4[2 * k],     ov0 = wo4[2 * k];
        float4 yv1 = y4[2 * k + 1], hv1 = wh4[2 * k + 1], ov1 = wo4[2 * k + 1];
        ah0 += yv0.x * hv0.x + yv0.y * hv0.y + yv0.z * hv0.z + yv0.w * hv0.w;
        ah1 += yv1.x * hv1.x + yv1.y * hv1.y + yv1.z * hv1.z + yv1.w * hv1.w;
        ao0 += yv0.x * ov0.x + yv0.y * ov0.y + yv0.z * ov0.z + yv0.w * ov0.w;
        ao1 += yv1.x * ov1.x + yv1.y * ov1.y + yv1.z * ov1.z + yv1.w * ov1.w;
    }
    h[idx] = ah0 + ah1;
    o[idx] = ao0 + ao1;
}

// ---------------------------------------------------------------------------
// Kernel 3: ONE WAVE PER *PAIR* OF QUERIES (r0=2u, r1=2u+1). 4 waves/block,
// zero __syncthreads. Each o_j row load feeds BOTH queries' tanh sums;
// each y_j row load feeds both ctx accumulations; W_out rows shared by both
// output rows. Halves per-query global-load stall chains.
// ---------------------------------------------------------------------------
__global__ void __launch_bounds__(256) k_att(
        const float* __restrict__ y,
        const float* __restrict__ h,
        const float* __restrict__ o,
        const float* __restrict__ V,
        const float* __restrict__ W_out,
        const float* __restrict__ b_out,
        float* __restrict__ out) {
    __shared__ float att_lds[4][2][T_];
    __shared__ float ctx_lds[4][2][H_];

    const int t    = threadIdx.x;
    const int w    = __builtin_amdgcn_readfirstlane(t >> 6);  // wave 0..3
    const int lane = t & 63;
    const int u    = blockIdx.x * 4 + w;     // pair unit
    const int r0   = 2 * u;                  // global row of query 0
    const int r1   = r0 + 1;
    const int bb   = r0 >> 8;                // batch

    // ---- preamble: h rows (vectorized), V ----
    float hs0[H_], hs1[H_];   // wave-uniform, kept in VGPRs (SGPR budget!)
    float w2[H_];             // rfl -> SGPR
    float vsum = 0.f;
    {
        const float4* h04 = reinterpret_cast<const float4*>(h + r0 * H_);
        const float4* h14 = reinterpret_cast<const float4*>(h + r1 * H_);
        const float4* V4  = reinterpret_cast<const float4*>(V);
        #pragma unroll
        for (int p = 0; p < 8; ++p) {
            float4 a = h04[p], b = h14[p], v = V4[p];
            hs0[4 * p + 0] = a.x * C2L2E; hs0[4 * p + 1] = a.y * C2L2E;
            hs0[4 * p + 2] = a.z * C2L2E; hs0[4 * p + 3] = a.w * C2L2E;
            hs1[4 * p + 0] = b.x * C2L2E; hs1[4 * p + 1] = b.y * C2L2E;
            hs1[4 * p + 2] = b.z * C2L2E; hs1[4 * p + 3] = b.w * C2L2E;
            w2[4 * p + 0] = rfl(v.x * -2.0f); w2[4 * p + 1] = rfl(v.y * -2.0f);
            w2[4 * p + 2] = rfl(v.z * -2.0f); w2[4 * p + 3] = rfl(v.w * -2.0f);
            vsum += v.x + v.y + v.z + v.w;
        }
        vsum = rfl(vsum);
    }

    const float* obase = o + (bb * T_) * H_;

    // ---- e for 4 j's per lane, both queries ----
    float E0[4], E1[4];
    #pragma unroll
    for (int q = 0; q < 4; ++q) {
        const int j = lane + 64 * q;
        const float4* o4 = reinterpret_cast<const float4*>(obase + j * H_);
        float4 ov[8];
        #pragma unroll
        for (int p = 0; p < 8; ++p) ov[p] = o4[p];
        float a00 = 0.f, a01 = 0.f, a02 = 0.f, a03 = 0.f;
        float a10 = 0.f, a11 = 0.f, a12 = 0.f, a13 = 0.f;
        #pragma unroll
        for (int p = 0; p < 8; ++p) {
            float oc0 = ov[p].x, oc1 = ov[p].y, oc2 = ov[p].z, oc3 = ov[p].w;
            a00 = fmaf(w2[4 * p + 0], sig_core(oc0, hs0[4 * p + 0]), a00);
            a10 = fmaf(w2[4 * p + 0], sig_core(oc0, hs1[4 * p + 0]), a10);
            a01 = fmaf(w2[4 * p + 1], sig_core(oc1, hs0[4 * p + 1]), a01);
            a11 = fmaf(w2[4 * p + 1], sig_core(oc1, hs1[4 * p + 1]), a11);
            a02 = fmaf(w2[4 * p + 2], sig_core(oc2, hs0[4 * p + 2]), a02);
            a12 = fmaf(w2[4 * p + 2], sig_core(oc2, hs1[4 * p + 2]), a12);
            a03 = fmaf(w2[4 * p + 3], sig_core(oc3, hs0[4 * p + 3]), a03);
            a13 = fmaf(w2[4 * p + 3], sig_core(oc3, hs1[4 * p + 3]), a13);
        }
        E0[q] = ((a00 + a01) + (a02 + a03)) + vsum;
        E1[q] = ((a10 + a11) + (a12 + a13)) + vsum;
    }

    // ---- wave-local softmax (no barriers), per query ----
    float m0 = fmaxf(fmaxf(E0[0], E0[1]), fmaxf(E0[2], E0[3]));
    float m1 = fmaxf(fmaxf(E1[0], E1[1]), fmaxf(E1[2], E1[3]));
    #pragma unroll
    for (int off = 1; off < 64; off <<= 1) {
        m0 = fmaxf(m0, __shfl_xor(m0, off));
        m1 = fmaxf(m1, __shfl_xor(m1, off));
    }
    float s0 = 0.f, s1 = 0.f;
    #pragma unroll
    for (int q = 0; q < 4; ++q) {
        s0 += __builtin_amdgcn_exp2f((E0[q] - m0) * L2E);
        s1 += __builtin_amdgcn_exp2f((E1[q] - m1) * L2E);
    }
    #pragma unroll
    for (int off = 1; off < 64; off <<= 1) {
        s0 += __shfl_xor(s0, off);
        s1 += __shfl_xor(s1, off);
    }
    const float lse0 = m0 + __builtin_amdgcn_logf(s0) * LN2;
    const float lse1 = m1 + __builtin_amdgcn_logf(s1) * LN2;

    #pragma unroll
    for (int q = 0; q < 4; ++q) {
        att_lds[w][0][lane + 64 * q] = E0[q] - lse0;
        att_lds[w][1][lane + 64 * q] = E1[q] - lse1;
    }
    // same-wave LDS produce->consume: ordered by lgkmcnt, no barrier needed

    // ---- context: lane = (jslice 0..7) x (channel-group 0..7) ----
    // ctx[q][4hg..4hg+3] = sum_j att[q][j] * y[j][4hg..4hg+3]
    {
        const int hg = lane & 7;
        const int js = lane >> 3;
        const float* ybase = y + (bb * T_) * H_ + hg * 4;
        float4 c0a = {0,0,0,0}, c0b = {0,0,0,0};
        float4 c1a = {0,0,0,0}, c1b = {0,0,0,0};
        #pragma unroll
        for (int n = 0; n < 32; n += 2) {
            int j0 = js * 32 + n, j1 = j0 + 1;
            float4 yv0 = *reinterpret_cast<const float4*>(ybase + j0 * H_);
            float4 yv1 = *reinterpret_cast<const float4*>(ybase + j1 * H_);
            float a00 = att_lds[w][0][j0], a01 = att_lds[w][0][j1];
            float a10 = att_lds[w][1][j0], a11 = att_lds[w][1][j1];
            c0a.x = fmaf(a00, yv0.x, c0a.x); c0a.y = fmaf(a00, yv0.y, c0a.y);
            c0a.z = fmaf(a00, yv0.z, c0a.z); c0a.w = fmaf(a00, yv0.w, c0a.w);
            c0b.x = fmaf(a01, yv1.x, c0b.x); c0b.y = fmaf(a01, yv1.y, c0b.y);
            c0b.z = fmaf(a01, yv1.z, c0b.z); c0b.w = fmaf(a01, yv1.w, c0b.w);
            c1a.x = fmaf(a10, yv0.x, c1a.x); c1a.y = fmaf(a10, yv0.y, c1a.y);
            c1a.z = fmaf(a10, yv0.z, c1a.z); c1a.w = fmaf(a10, yv0.w, c1a.w);
            c1b.x = fmaf(a11, yv1.x, c1b.x); c1b.y = fmaf(a11, yv1.y, c1b.y);
            c1b.z = fmaf(a11, yv1.z, c1b.z); c1b.w = fmaf(a11, yv1.w, c1b.w);
        }
        float4 c0, c1;
        c0.x = c0a.x + c0b.x; c0.y = c0a.y + c0b.y;
        c0.z = c0a.z + c0b.z; c0.w = c0a.w + c0b.w;
        c1.x = c1a.x + c1b.x; c1.y = c1a.y + c1b.y;
        c1.z = c1a.z + c1b.z; c1.w = c1a.w + c1b.w;
        // reduce over jslice axis (lane bits 3,4,5)
        #pragma unroll
        for (int off = 8; off < 64; off <<= 1) {
            c0.x += __shfl_xor(c0.x, off); c0.y += __shfl_xor(c0.y, off);
            c0.z += __shfl_xor(c0.z, off); c0.w += __shfl_xor(c0.w, off);
            c1.x += __shfl_xor(c1.x, off); c1.y += __shfl_xor(c1.y, off);
            c1.z += __shfl_xor(c1.z, off); c1.w += __shfl_xor(c1.w, off);
        }
        if (js == 0) {
            *reinterpret_cast<float4*>(&ctx_lds[w][0][4 * hg]) = c0;
            *reinterpret_cast<float4*>(&ctx_lds[w][1][4 * hg]) = c1;
        }
    }

    // ---- output projection: 2 channels/lane x 2 queries, W_out shared ----
    float4 cv0[8], cv1[8];
    #pragma unroll
    for (int p = 0; p < 8; ++p) {
        cv0[p] = *reinterpret_cast<const float4*>(&ctx_lds[w][0][4 * p]);
        cv1[p] = *reinterpret_cast<const float4*>(&ctx_lds[w][1][4 * p]);
    }
    #pragma unroll
    for (int ho = 0; ho < 2; ++ho) {
        const int oc = lane + 64 * ho;
        const float4* w4 = reinterpret_cast<const float4*>(W_out + oc * H_);
        float b  = b_out[oc];
        float p0 = 0.f, p0b = 0.f, p1 = 0.f, p1b = 0.f;
        #pragma unroll
        for (int p = 0; p < 8; p += 2) {
            float4 wv0 = w4[p], wv1 = w4[p + 1];
            p0  += wv0.x * cv0[p].x + wv0.y * cv0[p].y + wv0.z * cv0[p].z + wv0.w * cv0[p].w;
            p0b += wv1.x * cv0[p+1].x + wv1.y * cv0[p+1].y + wv1.z * cv0[p+1].z + wv1.w * cv0[p+1].w;
            p1  += wv0.x * cv1[p].x + wv0.y * cv1[p].y + wv0.z * cv1[p].z + wv0.w * cv1[p].w;
            p1b += wv1.x * cv1[p+1].x + wv1.y * cv1[p+1].y + wv1.z * cv1[p+1].z + wv1.w * cv1[p+1].w;
        }
        out[r0 * NOUT_ + oc] = b + p0 + p0b;
        out[r1 * NOUT_ + oc] = b + p1 + p1b;
    }
}

// ---------------------------------------------------------------------------
extern "C" void kernel_launch(void* const* d_in, const int* in_sizes, int n_in,
                              void* d_out, int out_size, void* d_ws, size_t ws_size,
                              hipStream_t stream) {
    const float* x     = (const float*)d_in[0];
    const float* W_in  = (const float*)d_in[1];
    const float* b_in  = (const float*)d_in[2];
    const float* W_h   = (const float*)d_in[3];
    const float* W_o   = (const float*)d_in[4];
    const float* V     = (const float*)d_in[5];
    const float* W_out = (const float*)d_in[6];
    const float* b_out = (const float*)d_in[7];
    float* out = (float*)d_out;

    // workspace layout: y | h | o  (each R_*H_ floats = 1 MB)
    float* y = (float*)d_ws;
    float* h = y + R_ * H_;
    float* o = h + R_ * H_;

    k_y <<<R_ * H_ / 256, 256, 0, stream>>>(x, W_in, b_in, y);
    k_ho<<<R_ * H_ / 256, 256, 0, stream>>>(y, W_h, W_o, h, o);
    k_att<<<R_ / 8, 256, 0, stream>>>(y, h, o, V, W_out, b_out, out);
}

// Round 7
// 60.163 us; speedup vs baseline: 2.0367x; 1.0602x over previous
//
#include <hip/hip_runtime.h>
#include <hip/hip_bf16.h>

#define B_ 32
#define T_ 256
#define NIN_ 128
#define H_ 32
#define NOUT_ 128
#define R_ (B_ * T_)   // 8192 rows

#define C2L2E 2.88539008177792681472f   // 2*log2(e)
#define L2E   1.44269504088896341f
#define LN2   0.69314718055994531f

__device__ __forceinline__ float rfl(float x) {
    return __uint_as_float(__builtin_amdgcn_readfirstlane(__float_as_uint(x)));
}

// sigmoid core: rcp(exp2(o*2log2e + hpre) + 1);  tanh(hi+o) = 1 - 2*sig
__device__ __forceinline__ float sig_core(float o, float hpre) {
    float ex = __builtin_amdgcn_exp2f(fmaf(o, C2L2E, hpre));
    return __builtin_amdgcn_rcpf(ex + 1.0f);
}

// ---------------------------------------------------------------------------
// Kernel 1: y[row][h] = dot(x[row,:], W_in[h,:]) + b_in[h]
// ---------------------------------------------------------------------------
__global__ void __launch_bounds__(256) k_y(
        const float* __restrict__ x,
        const float* __restrict__ W_in,
        const float* __restrict__ b_in,
        float* __restrict__ y) {
    int idx = blockIdx.x * blockDim.x + threadIdx.x;
    int row = idx >> 5;
    int hh  = idx & 31;
    const float4* x4 = reinterpret_cast<const float4*>(x + row * NIN_);
    const float4* w4 = reinterpret_cast<const float4*>(W_in + hh * NIN_);
    float a0 = b_in[hh], a1 = 0.f;
    #pragma unroll
    for (int k = 0; k < NIN_ / 8; ++k) {
        float4 xv0 = x4[2 * k],     wv0 = w4[2 * k];
        float4 xv1 = x4[2 * k + 1], wv1 = w4[2 * k + 1];
        a0 += xv0.x * wv0.x + xv0.y * wv0.y + xv0.z * wv0.z + xv0.w * wv0.w;
        a1 += xv1.x * wv1.x + xv1.y * wv1.y + xv1.z * wv1.z + xv1.w * wv1.w;
    }
    y[idx] = a0 + a1;
}

// ---------------------------------------------------------------------------
// Kernel 2: h = y @ W_h^T ; o = y @ W_o^T
// ---------------------------------------------------------------------------
__global__ void __launch_bounds__(256) k_ho(
        const float* __restrict__ y,
        const float* __restrict__ W_h,
        const float* __restrict__ W_o,
        float* __restrict__ h,
        float* __restrict__ o) {
    int idx = blockIdx.x * blockDim.x + threadIdx.x;
    int row = idx >> 5;
    int g   = idx & 31;
    const float4* y4  = reinterpret_cast<const float4*>(y + row * H_);
    const float4* wh4 = reinterpret_cast<const float4*>(W_h + g * H_);
    const float4* wo4 = reinterpret_cast<const float4*>(W_o + g * H_);
    float ah0 = 0.f, ah1 = 0.f, ao0 = 0.f, ao1 = 0.f;
    #pragma unroll
    for (int k = 0; k < H_ / 8; ++k) {
        float4 yv0 = y4[2 * k],     hv0 = wh4[2 * k],     ov0 = wo4[2 * k];
        float4 yv1 = y4[2 * k + 1], hv1 = wh4[2 * k + 1], ov1 = wo4[2 * k + 1];
        ah0 += yv0.x * hv0.x + yv0.y * hv0.y + yv0.z * hv0.z + yv0.w * hv0.w;
        ah1 += yv1.x * hv1.x + yv1.y * hv1.y + yv1.z * hv1.z + yv1.w * hv1.w;
        ao0 += yv0.x * ov0.x + yv0.y * ov0.y + yv0.z * ov0.z + yv0.w * ov0.w;
        ao1 += yv1.x * ov1.x + yv1.y * ov1.y + yv1.z * ov1.z + yv1.w * ov1.w;
    }
    h[idx] = ah0 + ah1;
    o[idx] = ao0 + ao1;
}

// ---------------------------------------------------------------------------
// Kernel 3: block = 4 waves = 8 consecutive queries, one batch bb.
// Stage o-tile AND y-tile [256][32] in LDS ONCE per block (XOR-swizzled
// 16B chunks: chunk p of row j stored at slot p^(j&7) -> conflict-free for
// BOTH row-reads (e-phase) and chunk-column reads (ctx-phase)).
// After one __syncthreads, all loops are LDS+VALU only; zero global loads.
// att stored transposed (idx n*8+js) to spread ctx reads across banks.
// ---------------------------------------------------------------------------
__global__ void __launch_bounds__(256) k_att(
        const float* __restrict__ y,
        const float* __restrict__ h,
        const float* __restrict__ o,
        const float* __restrict__ V,
        const float* __restrict__ W_out,
        const float* __restrict__ b_out,
        float* __restrict__ out) {
    __shared__ float o_swz[T_ * H_];       // 32 KB
    __shared__ float y_swz[T_ * H_];       // 32 KB
    __shared__ float att_t[4][2][T_];      // 8 KB, transposed index
    __shared__ float ctx_lds[4][2][H_];    // 1 KB

    const int t    = threadIdx.x;
    const int w    = __builtin_amdgcn_readfirstlane(t >> 6);  // wave 0..3
    const int lane = t & 63;
    const int u    = blockIdx.x * 4 + w;     // pair unit
    const int r0   = 2 * u;                  // query rows r0, r0+1
    const int r1   = r0 + 1;
    const int bb   = blockIdx.x >> 5;        // batch (8 queries/block, 32 blocks/batch)

    // ---- stage o-tile and y-tile (swizzled), all 256 threads ----
    {
        const float4* og = reinterpret_cast<const float4*>(o + bb * T_ * H_);
        const float4* yg = reinterpret_cast<const float4*>(y + bb * T_ * H_);
        float4 ot[8], yt[8];
        #pragma unroll
        for (int n = 0; n < 8; ++n) {
            ot[n] = og[n * 256 + t];
            yt[n] = yg[n * 256 + t];
        }
        #pragma unroll
        for (int n = 0; n < 8; ++n) {
            int c = n * 256 + t;
            int j = c >> 3, p = c & 7;
            int dst = j * H_ + (((p ^ j) & 7) << 2);
            *reinterpret_cast<float4*>(&o_swz[dst]) = ot[n];
            *reinterpret_cast<float4*>(&y_swz[dst]) = yt[n];
        }
    }
    __syncthreads();

    // ---- preamble: h rows (vectorized), V ----
    float hs0[H_], hs1[H_];   // wave-uniform, kept in VGPRs (SGPR budget!)
    float w2[H_];             // rfl -> SGPR
    float vsum = 0.f;
    {
        const float4* h04 = reinterpret_cast<const float4*>(h + r0 * H_);
        const float4* h14 = reinterpret_cast<const float4*>(h + r1 * H_);
        const float4* V4  = reinterpret_cast<const float4*>(V);
        #pragma unroll
        for (int p = 0; p < 8; ++p) {
            float4 a = h04[p], b = h14[p], v = V4[p];
            hs0[4 * p + 0] = a.x * C2L2E; hs0[4 * p + 1] = a.y * C2L2E;
            hs0[4 * p + 2] = a.z * C2L2E; hs0[4 * p + 3] = a.w * C2L2E;
            hs1[4 * p + 0] = b.x * C2L2E; hs1[4 * p + 1] = b.y * C2L2E;
            hs1[4 * p + 2] = b.z * C2L2E; hs1[4 * p + 3] = b.w * C2L2E;
            w2[4 * p + 0] = rfl(v.x * -2.0f); w2[4 * p + 1] = rfl(v.y * -2.0f);
            w2[4 * p + 2] = rfl(v.z * -2.0f); w2[4 * p + 3] = rfl(v.w * -2.0f);
            vsum += v.x + v.y + v.z + v.w;
        }
        vsum = rfl(vsum);
    }

    // ---- e for 4 j's per lane, both queries; o rows from LDS ----
    float E0[4], E1[4];
    #pragma unroll
    for (int q = 0; q < 4; ++q) {
        const int j  = lane + 64 * q;
        const int jb = j * H_;
        const int jx = (j & 7) << 2;
        float4 ov[8];
        #pragma unroll
        for (int p = 0; p < 8; ++p)
            ov[p] = *reinterpret_cast<const float4*>(&o_swz[jb + ((p << 2) ^ jx)]);
        float a00 = 0.f, a01 = 0.f, a02 = 0.f, a03 = 0.f;
        float a10 = 0.f, a11 = 0.f, a12 = 0.f, a13 = 0.f;
        #pragma unroll
        for (int p = 0; p < 8; ++p) {
            float oc0 = ov[p].x, oc1 = ov[p].y, oc2 = ov[p].z, oc3 = ov[p].w;
            a00 = fmaf(w2[4 * p + 0], sig_core(oc0, hs0[4 * p + 0]), a00);
            a10 = fmaf(w2[4 * p + 0], sig_core(oc0, hs1[4 * p + 0]), a10);
            a01 = fmaf(w2[4 * p + 1], sig_core(oc1, hs0[4 * p + 1]), a01);
            a11 = fmaf(w2[4 * p + 1], sig_core(oc1, hs1[4 * p + 1]), a11);
            a02 = fmaf(w2[4 * p + 2], sig_core(oc2, hs0[4 * p + 2]), a02);
            a12 = fmaf(w2[4 * p + 2], sig_core(oc2, hs1[4 * p + 2]), a12);
            a03 = fmaf(w2[4 * p + 3], sig_core(oc3, hs0[4 * p + 3]), a03);
            a13 = fmaf(w2[4 * p + 3], sig_core(oc3, hs1[4 * p + 3]), a13);
        }
        E0[q] = ((a00 + a01) + (a02 + a03)) + vsum;
        E1[q] = ((a10 + a11) + (a12 + a13)) + vsum;
    }

    // ---- wave-local softmax (no barriers), per query ----
    float m0 = fmaxf(fmaxf(E0[0], E0[1]), fmaxf(E0[2], E0[3]));
    float m1 = fmaxf(fmaxf(E1[0], E1[1]), fmaxf(E1[2], E1[3]));
    #pragma unroll
    for (int off = 1; off < 64; off <<= 1) {
        m0 = fmaxf(m0, __shfl_xor(m0, off));
        m1 = fmaxf(m1, __shfl_xor(m1, off));
    }
    float s0 = 0.f, s1 = 0.f;
    #pragma unroll
    for (int q = 0; q < 4; ++q) {
        s0 += __builtin_amdgcn_exp2f((E0[q] - m0) * L2E);
        s1 += __builtin_amdgcn_exp2f((E1[q] - m1) * L2E);
    }
    #pragma unroll
    for (int off = 1; off < 64; off <<= 1) {
        s0 += __shfl_xor(s0, off);
        s1 += __shfl_xor(s1, off);
    }
    const float lse0 = m0 + __builtin_amdgcn_logf(s0) * LN2;
    const float lse1 = m1 + __builtin_amdgcn_logf(s1) * LN2;

    // transposed store: att_t[.][.][ (j&31)*8 + (j>>5) ]
    #pragma unroll
    for (int q = 0; q < 4; ++q) {
        const int j = lane + 64 * q;
        const int ti = (j & 31) * 8 + (j >> 5);
        att_t[w][0][ti] = E0[q] - lse0;
        att_t[w][1][ti] = E1[q] - lse1;
    }
    // same-wave LDS produce->consume: ordered by lgkmcnt, no barrier needed

    // ---- context: lane = (channel-group hg 0..7) x (jslice js 0..7) ----
    {
        const int hg = lane & 7;
        const int js = lane >> 3;
        float4 c0 = {0, 0, 0, 0}, c1 = {0, 0, 0, 0};
        #pragma unroll
        for (int n = 0; n < 32; ++n) {
            const int j = js * 32 + n;
            float4 yv = *reinterpret_cast<const float4*>(
                &y_swz[j * H_ + (((hg ^ n) & 7) << 2)]);
            float a0 = att_t[w][0][n * 8 + js];
            float a1 = att_t[w][1][n * 8 + js];
            c0.x = fmaf(a0, yv.x, c0.x); c0.y = fmaf(a0, yv.y, c0.y);
            c0.z = fmaf(a0, yv.z, c0.z); c0.w = fmaf(a0, yv.w, c0.w);
            c1.x = fmaf(a1, yv.x, c1.x); c1.y = fmaf(a1, yv.y, c1.y);
            c1.z = fmaf(a1, yv.z, c1.z); c1.w = fmaf(a1, yv.w, c1.w);
        }
        // reduce over js axis (lane bits 3,4,5)
        #pragma unroll
        for (int off = 8; off < 64; off <<= 1) {
            c0.x += __shfl_xor(c0.x, off); c0.y += __shfl_xor(c0.y, off);
            c0.z += __shfl_xor(c0.z, off); c0.w += __shfl_xor(c0.w, off);
            c1.x += __shfl_xor(c1.x, off); c1.y += __shfl_xor(c1.y, off);
            c1.z += __shfl_xor(c1.z, off); c1.w += __shfl_xor(c1.w, off);
        }
        if (js == 0) {
            *reinterpret_cast<float4*>(&ctx_lds[w][0][4 * hg]) = c0;
            *reinterpret_cast<float4*>(&ctx_lds[w][1][4 * hg]) = c1;
        }
    }

    // ---- output projection: 2 channels/lane x 2 queries, W_out shared ----
    float4 cv0[8], cv1[8];
    #pragma unroll
    for (int p = 0; p < 8; ++p) {
        cv0[p] = *reinterpret_cast<const float4*>(&ctx_lds[w][0][4 * p]);
        cv1[p] = *reinterpret_cast<const float4*>(&ctx_lds[w][1][4 * p]);
    }
    #pragma unroll
    for (int ho = 0; ho < 2; ++ho) {
        const int oc = lane + 64 * ho;
        const float4* w4 = reinterpret_cast<const float4*>(W_out + oc * H_);
        float b  = b_out[oc];
        float p0 = 0.f, p0b = 0.f, p1 = 0.f, p1b = 0.f;
        #pragma unroll
        for (int p = 0; p < 8; p += 2) {
            float4 wv0 = w4[p], wv1 = w4[p + 1];
            p0  += wv0.x * cv0[p].x + wv0.y * cv0[p].y + wv0.z * cv0[p].z + wv0.w * cv0[p].w;
            p0b += wv1.x * cv0[p+1].x + wv1.y * cv0[p+1].y + wv1.z * cv0[p+1].z + wv1.w * cv0[p+1].w;
            p1  += wv0.x * cv1[p].x + wv0.y * cv1[p].y + wv0.z * cv1[p].z + wv0.w * cv1[p].w;
            p1b += wv1.x * cv1[p+1].x + wv1.y * cv1[p+1].y + wv1.z * cv1[p+1].z + wv1.w * cv1[p+1].w;
        }
        out[r0 * NOUT_ + oc] = b + p0 + p0b;
        out[r1 * NOUT_ + oc] = b + p1 + p1b;
    }
}

// ---------------------------------------------------------------------------
extern "C" void kernel_launch(void* const* d_in, const int* in_sizes, int n_in,
                              void* d_out, int out_size, void* d_ws, size_t ws_size,
                              hipStream_t stream) {
    const float* x     = (const float*)d_in[0];
    const float* W_in  = (const float*)d_in[1];
    const float* b_in  = (const float*)d_in[2];
    const float* W_h   = (const float*)d_in[3];
    const float* W_o   = (const float*)d_in[4];
    const float* V     = (const float*)d_in[5];
    const float* W_out = (const float*)d_in[6];
    const float* b_out = (const float*)d_in[7];
    float* out = (float*)d_out;

    // workspace layout: y | h | o  (each R_*H_ floats = 1 MB)
    float* y = (float*)d_ws;
    float* h = y + R_ * H_;
    float* o = h + R_ * H_;

    k_y <<<R_ * H_ / 256, 256, 0, stream>>>(x, W_in, b_in, y);
    k_ho<<<R_ * H_ / 256, 256, 0, stream>>>(y, W_h, W_o, h, o);
    k_att<<<R_ / 8, 256, 0, stream>>>(y, h, o, V, W_out, b_out, out);
}

// Round 8
// 54.921 us; speedup vs baseline: 2.2311x; 1.0954x over previous
//
#include <hip/hip_runtime.h>
#include <hip/hip_bf16.h>

#define B_ 32
#define T_ 256
#define NIN_ 128
#define H_ 32
#define NOUT_ 128
#define R_ (B_ * T_)   // 8192 rows

#define C2L2E 2.88539008177792681472f   // 2*log2(e)
#define L2E   1.44269504088896341f
#define LN2   0.69314718055994531f

__device__ __forceinline__ float rfl(float x) {
    return __uint_as_float(__builtin_amdgcn_readfirstlane(__float_as_uint(x)));
}

// ---------------------------------------------------------------------------
// Kernel 1: y[row][h] = dot(x[row,:], W_in[h,:]) + b_in[h]
// ---------------------------------------------------------------------------
__global__ void __launch_bounds__(256) k_y(
        const float* __restrict__ x,
        const float* __restrict__ W_in,
        const float* __restrict__ b_in,
        float* __restrict__ y) {
    int idx = blockIdx.x * blockDim.x + threadIdx.x;
    int row = idx >> 5;
    int hh  = idx & 31;
    const float4* x4 = reinterpret_cast<const float4*>(x + row * NIN_);
    const float4* w4 = reinterpret_cast<const float4*>(W_in + hh * NIN_);
    float a0 = b_in[hh], a1 = 0.f;
    #pragma unroll
    for (int k = 0; k < NIN_ / 8; ++k) {
        float4 xv0 = x4[2 * k],     wv0 = w4[2 * k];
        float4 xv1 = x4[2 * k + 1], wv1 = w4[2 * k + 1];
        a0 += xv0.x * wv0.x + xv0.y * wv0.y + xv0.z * wv0.z + xv0.w * wv0.w;
        a1 += xv1.x * wv1.x + xv1.y * wv1.y + xv1.z * wv1.z + xv1.w * wv1.w;
    }
    y[idx] = a0 + a1;
}

// ---------------------------------------------------------------------------
// Kernel 2: Eh = exp2(2log2e * y@W_h^T) ; Eo = exp2(2log2e * y@W_o^T)
// (exp factorization: exp(2(h_i+o_j)) = Eh_i * Eo_j moves the exp out of the
//  67M-element pair loop into this 262k-element projection.)
// ---------------------------------------------------------------------------
__global__ void __launch_bounds__(256) k_ho(
        const float* __restrict__ y,
        const float* __restrict__ W_h,
        const float* __restrict__ W_o,
        float* __restrict__ Eh,
        float* __restrict__ Eo) {
    int idx = blockIdx.x * blockDim.x + threadIdx.x;
    int row = idx >> 5;
    int g   = idx & 31;
    const float4* y4  = reinterpret_cast<const float4*>(y + row * H_);
    const float4* wh4 = reinterpret_cast<const float4*>(W_h + g * H_);
    const float4* wo4 = reinterpret_cast<const float4*>(W_o + g * H_);
    float ah0 = 0.f, ah1 = 0.f, ao0 = 0.f, ao1 = 0.f;
    #pragma unroll
    for (int k = 0; k < H_ / 8; ++k) {
        float4 yv0 = y4[2 * k],     hv0 = wh4[2 * k],     ov0 = wo4[2 * k];
        float4 yv1 = y4[2 * k + 1], hv1 = wh4[2 * k + 1], ov1 = wo4[2 * k + 1];
        ah0 += yv0.x * hv0.x + yv0.y * hv0.y + yv0.z * hv0.z + yv0.w * hv0.w;
        ah1 += yv1.x * hv1.x + yv1.y * hv1.y + yv1.z * hv1.z + yv1.w * hv1.w;
        ao0 += yv0.x * ov0.x + yv0.y * ov0.y + yv0.z * ov0.z + yv0.w * ov0.w;
        ao1 += yv1.x * ov1.x + yv1.y * ov1.y + yv1.z * ov1.z + yv1.w * ov1.w;
    }
    Eh[idx] = __builtin_amdgcn_exp2f((ah0 + ah1) * C2L2E);
    Eo[idx] = __builtin_amdgcn_exp2f((ao0 + ao1) * C2L2E);
}

// ---------------------------------------------------------------------------
// Kernel 3: block = 8 waves = 16 queries of one batch bb (512 threads).
// Stage Eo tile [256][32] once per block, XOR-swizzled 16B chunks
// (chunk p of row j at slot p^(j&7): conflict-free for staging writes and
// row-reads under 8-lane phasing). LDS ~51KB -> occupancy limited by grid
// (2 blocks/CU = 4 waves/SIMD), not LDS.
// Inner element: tanh-term via rcp(fma(Eh[k], Eo[j][k], 1)) — 1 trans+2 VALU.
// ctx phase reads y from global (L2-resident, independent pipelined loads).
// ---------------------------------------------------------------------------
__global__ void __launch_bounds__(512) k_att(
        const float* __restrict__ y,
        const float* __restrict__ Eh,
        const float* __restrict__ Eo,
        const float* __restrict__ V,
        const float* __restrict__ W_out,
        const float* __restrict__ b_out,
        float* __restrict__ out) {
    __shared__ float eo_swz[T_ * H_];      // 32 KB
    __shared__ float att_t[8][2][T_];      // 16 KB, transposed index
    __shared__ float ctx_lds[8][2][H_];    // 2 KB

    const int t    = threadIdx.x;
    const int w    = __builtin_amdgcn_readfirstlane(t >> 6);  // wave 0..7
    const int lane = t & 63;
    const int r0   = blockIdx.x * 16 + 2 * w;   // query rows r0, r0+1
    const int r1   = r0 + 1;
    const int bb   = blockIdx.x >> 4;           // batch (16 queries/block)

    // ---- stage Eo tile (swizzled), all 512 threads ----
    {
        const float4* eg = reinterpret_cast<const float4*>(Eo + bb * T_ * H_);
        float4 tmp[4];
        #pragma unroll
        for (int n = 0; n < 4; ++n) tmp[n] = eg[n * 512 + t];
        #pragma unroll
        for (int n = 0; n < 4; ++n) {
            int c = n * 512 + t;
            int j = c >> 3, p = c & 7;
            *reinterpret_cast<float4*>(&eo_swz[j * H_ + (((p ^ j) & 7) << 2)]) = tmp[n];
        }
    }
    __syncthreads();

    // ---- preamble: Eh rows (wave-uniform, VGPRs), V -> SGPRs ----
    float eh0[H_], eh1[H_];
    float w2[H_];
    float vsum = 0.f;
    {
        const float4* h04 = reinterpret_cast<const float4*>(Eh + r0 * H_);
        const float4* h14 = reinterpret_cast<const float4*>(Eh + r1 * H_);
        const float4* V4  = reinterpret_cast<const float4*>(V);
        #pragma unroll
        for (int p = 0; p < 8; ++p) {
            float4 a = h04[p], b = h14[p], v = V4[p];
            eh0[4 * p + 0] = a.x; eh0[4 * p + 1] = a.y;
            eh0[4 * p + 2] = a.z; eh0[4 * p + 3] = a.w;
            eh1[4 * p + 0] = b.x; eh1[4 * p + 1] = b.y;
            eh1[4 * p + 2] = b.z; eh1[4 * p + 3] = b.w;
            w2[4 * p + 0] = rfl(v.x * -2.0f); w2[4 * p + 1] = rfl(v.y * -2.0f);
            w2[4 * p + 2] = rfl(v.z * -2.0f); w2[4 * p + 3] = rfl(v.w * -2.0f);
            vsum += v.x + v.y + v.z + v.w;
        }
        vsum = rfl(vsum);
    }

    // ---- e for 4 j's per lane, both queries; Eo rows from LDS ----
    float E0[4], E1[4];
    #pragma unroll
    for (int q = 0; q < 4; ++q) {
        const int j  = lane + 64 * q;
        const int jb = j * H_;
        const int jx = (j & 7) << 2;
        float4 ev[8];
        #pragma unroll
        for (int p = 0; p < 8; ++p)
            ev[p] = *reinterpret_cast<const float4*>(&eo_swz[jb + ((p << 2) ^ jx)]);
        float a00 = 0.f, a01 = 0.f, a02 = 0.f, a03 = 0.f;
        float a10 = 0.f, a11 = 0.f, a12 = 0.f, a13 = 0.f;
        #pragma unroll
        for (int p = 0; p < 8; ++p) {
            const int k = 4 * p;
            float d;
            d = fmaf(eh0[k + 0], ev[p].x, 1.0f);
            a00 = fmaf(w2[k + 0], __builtin_amdgcn_rcpf(d), a00);
            d = fmaf(eh1[k + 0], ev[p].x, 1.0f);
            a10 = fmaf(w2[k + 0], __builtin_amdgcn_rcpf(d), a10);
            d = fmaf(eh0[k + 1], ev[p].y, 1.0f);
            a01 = fmaf(w2[k + 1], __builtin_amdgcn_rcpf(d), a01);
            d = fmaf(eh1[k + 1], ev[p].y, 1.0f);
            a11 = fmaf(w2[k + 1], __builtin_amdgcn_rcpf(d), a11);
            d = fmaf(eh0[k + 2], ev[p].z, 1.0f);
            a02 = fmaf(w2[k + 2], __builtin_amdgcn_rcpf(d), a02);
            d = fmaf(eh1[k + 2], ev[p].z, 1.0f);
            a12 = fmaf(w2[k + 2], __builtin_amdgcn_rcpf(d), a12);
            d = fmaf(eh0[k + 3], ev[p].w, 1.0f);
            a03 = fmaf(w2[k + 3], __builtin_amdgcn_rcpf(d), a03);
            d = fmaf(eh1[k + 3], ev[p].w, 1.0f);
            a13 = fmaf(w2[k + 3], __builtin_amdgcn_rcpf(d), a13);
        }
        E0[q] = ((a00 + a01) + (a02 + a03)) + vsum;
        E1[q] = ((a10 + a11) + (a12 + a13)) + vsum;
    }

    // ---- wave-local softmax (no barriers), per query ----
    float m0 = fmaxf(fmaxf(E0[0], E0[1]), fmaxf(E0[2], E0[3]));
    float m1 = fmaxf(fmaxf(E1[0], E1[1]), fmaxf(E1[2], E1[3]));
    #pragma unroll
    for (int off = 1; off < 64; off <<= 1) {
        m0 = fmaxf(m0, __shfl_xor(m0, off));
        m1 = fmaxf(m1, __shfl_xor(m1, off));
    }
    float s0 = 0.f, s1 = 0.f;
    #pragma unroll
    for (int q = 0; q < 4; ++q) {
        s0 += __builtin_amdgcn_exp2f((E0[q] - m0) * L2E);
        s1 += __builtin_amdgcn_exp2f((E1[q] - m1) * L2E);
    }
    #pragma unroll
    for (int off = 1; off < 64; off <<= 1) {
        s0 += __shfl_xor(s0, off);
        s1 += __shfl_xor(s1, off);
    }
    const float lse0 = m0 + __builtin_amdgcn_logf(s0) * LN2;
    const float lse1 = m1 + __builtin_amdgcn_logf(s1) * LN2;

    // transposed store: att_t[.][.][ (j&31)*8 + (j>>5) ]
    #pragma unroll
    for (int q = 0; q < 4; ++q) {
        const int j = lane + 64 * q;
        const int ti = (j & 31) * 8 + (j >> 5);
        att_t[w][0][ti] = E0[q] - lse0;
        att_t[w][1][ti] = E1[q] - lse1;
    }
    // same-wave LDS produce->consume: ordered by lgkmcnt, no barrier needed

    // ---- context: lane = (channel-group hg 0..7) x (jslice js 0..7),
    //      y rows from global (L2) — independent, pipelined loads ----
    {
        const int hg = lane & 7;
        const int js = lane >> 3;
        const float* ybase = y + bb * T_ * H_ + hg * 4;
        float4 c0 = {0, 0, 0, 0}, c1 = {0, 0, 0, 0};
        #pragma unroll
        for (int n = 0; n < 32; ++n) {
            const int j = js * 32 + n;
            float4 yv = *reinterpret_cast<const float4*>(ybase + j * H_);
            float a0 = att_t[w][0][n * 8 + js];
            float a1 = att_t[w][1][n * 8 + js];
            c0.x = fmaf(a0, yv.x, c0.x); c0.y = fmaf(a0, yv.y, c0.y);
            c0.z = fmaf(a0, yv.z, c0.z); c0.w = fmaf(a0, yv.w, c0.w);
            c1.x = fmaf(a1, yv.x, c1.x); c1.y = fmaf(a1, yv.y, c1.y);
            c1.z = fmaf(a1, yv.z, c1.z); c1.w = fmaf(a1, yv.w, c1.w);
        }
        // reduce over js axis (lane bits 3,4,5)
        #pragma unroll
        for (int off = 8; off < 64; off <<= 1) {
            c0.x += __shfl_xor(c0.x, off); c0.y += __shfl_xor(c0.y, off);
            c0.z += __shfl_xor(c0.z, off); c0.w += __shfl_xor(c0.w, off);
            c1.x += __shfl_xor(c1.x, off); c1.y += __shfl_xor(c1.y, off);
            c1.z += __shfl_xor(c1.z, off); c1.w += __shfl_xor(c1.w, off);
        }
        if (js == 0) {
            *reinterpret_cast<float4*>(&ctx_lds[w][0][4 * hg]) = c0;
            *reinterpret_cast<float4*>(&ctx_lds[w][1][4 * hg]) = c1;
        }
    }

    // ---- output projection: 2 channels/lane x 2 queries, W_out shared ----
    float4 cv0[8], cv1[8];
    #pragma unroll
    for (int p = 0; p < 8; ++p) {
        cv0[p] = *reinterpret_cast<const float4*>(&ctx_lds[w][0][4 * p]);
        cv1[p] = *reinterpret_cast<const float4*>(&ctx_lds[w][1][4 * p]);
    }
    #pragma unroll
    for (int ho = 0; ho < 2; ++ho) {
        const int oc = lane + 64 * ho;
        const float4* w4 = reinterpret_cast<const float4*>(W_out + oc * H_);
        float b  = b_out[oc];
        float p0 = 0.f, p0b = 0.f, p1 = 0.f, p1b = 0.f;
        #pragma unroll
        for (int p = 0; p < 8; p += 2) {
            float4 wv0 = w4[p], wv1 = w4[p + 1];
            p0  += wv0.x * cv0[p].x + wv0.y * cv0[p].y + wv0.z * cv0[p].z + wv0.w * cv0[p].w;
            p0b += wv1.x * cv0[p+1].x + wv1.y * cv0[p+1].y + wv1.z * cv0[p+1].z + wv1.w * cv0[p+1].w;
            p1  += wv0.x * cv1[p].x + wv0.y * cv1[p].y + wv0.z * cv1[p].z + wv0.w * cv1[p].w;
            p1b += wv1.x * cv1[p+1].x + wv1.y * cv1[p+1].y + wv1.z * cv1[p+1].z + wv1.w * cv1[p+1].w;
        }
        out[r0 * NOUT_ + oc] = b + p0 + p0b;
        out[r1 * NOUT_ + oc] = b + p1 + p1b;
    }
}

// ---------------------------------------------------------------------------
extern "C" void kernel_launch(void* const* d_in, const int* in_sizes, int n_in,
                              void* d_out, int out_size, void* d_ws, size_t ws_size,
                              hipStream_t stream) {
    const float* x     = (const float*)d_in[0];
    const float* W_in  = (const float*)d_in[1];
    const float* b_in  = (const float*)d_in[2];
    const float* W_h   = (const float*)d_in[3];
    const float* W_o   = (const float*)d_in[4];
    const float* V     = (const float*)d_in[5];
    const float* W_out = (const float*)d_in[6];
    const float* b_out = (const float*)d_in[7];
    float* out = (float*)d_out;

    // workspace layout: y | Eh | Eo  (each R_*H_ floats = 1 MB)
    float* y  = (float*)d_ws;
    float* Eh = y + R_ * H_;
    float* Eo = Eh + R_ * H_;

    k_y <<<R_ * H_ / 256, 256, 0, stream>>>(x, W_in, b_in, y);
    k_ho<<<R_ * H_ / 256, 256, 0, stream>>>(y, W_h, W_o, Eh, Eo);
    k_att<<<R_ / 16, 512, 0, stream>>>(y, Eh, Eo, V, W_out, b_out, out);
}

// Round 9
// 51.046 us; speedup vs baseline: 2.4004x; 1.0759x over previous
//
#include <hip/hip_runtime.h>
#include <hip/hip_bf16.h>

#define B_ 32
#define T_ 256
#define NIN_ 128
#define H_ 32
#define NOUT_ 128
#define R_ (B_ * T_)   // 8192 rows

#define C2L2E 2.88539008177792681472f   // 2*log2(e)
#define L2E   1.44269504088896341f
#define LN2   0.69314718055994531f

__device__ __forceinline__ float rfl(float x) {
    return __uint_as_float(__builtin_amdgcn_readfirstlane(__float_as_uint(x)));
}

// ---------------------------------------------------------------------------
// Kernel 1 (fused): per block = 8 rows x 32 h (256 threads).
//   y = x @ W_in^T + b_in (LDS-staged), Eh = exp2(c*y@W_h^T), Eo = exp2(c*y@W_o^T)
// ---------------------------------------------------------------------------
__global__ void __launch_bounds__(256) k_yho(
        const float* __restrict__ x,
        const float* __restrict__ W_in,
        const float* __restrict__ b_in,
        const float* __restrict__ W_h,
        const float* __restrict__ W_o,
        float* __restrict__ y,
        float* __restrict__ Eh,
        float* __restrict__ Eo) {
    __shared__ float ys[8][H_];
    const int t   = threadIdx.x;
    const int r   = t >> 5;              // local row 0..7
    const int hh  = t & 31;
    const int row = blockIdx.x * 8 + r;
    const int idx = row * H_ + hh;

    {
        const float4* x4 = reinterpret_cast<const float4*>(x + row * NIN_);
        const float4* w4 = reinterpret_cast<const float4*>(W_in + hh * NIN_);
        float a0 = b_in[hh], a1 = 0.f;
        #pragma unroll
        for (int k = 0; k < NIN_ / 8; ++k) {
            float4 xv0 = x4[2 * k],     wv0 = w4[2 * k];
            float4 xv1 = x4[2 * k + 1], wv1 = w4[2 * k + 1];
            a0 += xv0.x * wv0.x + xv0.y * wv0.y + xv0.z * wv0.z + xv0.w * wv0.w;
            a1 += xv1.x * wv1.x + xv1.y * wv1.y + xv1.z * wv1.z + xv1.w * wv1.w;
        }
        float acc = a0 + a1;
        ys[r][hh] = acc;
        y[idx] = acc;
    }
    __syncthreads();

    {
        const float4* y4  = reinterpret_cast<const float4*>(&ys[r][0]);
        const float4* wh4 = reinterpret_cast<const float4*>(W_h + hh * H_);
        const float4* wo4 = reinterpret_cast<const float4*>(W_o + hh * H_);
        float ah0 = 0.f, ah1 = 0.f, ao0 = 0.f, ao1 = 0.f;
        #pragma unroll
        for (int k = 0; k < H_ / 8; ++k) {
            float4 yv0 = y4[2 * k],     hv0 = wh4[2 * k],     ov0 = wo4[2 * k];
            float4 yv1 = y4[2 * k + 1], hv1 = wh4[2 * k + 1], ov1 = wo4[2 * k + 1];
            ah0 += yv0.x * hv0.x + yv0.y * hv0.y + yv0.z * hv0.z + yv0.w * hv0.w;
            ah1 += yv1.x * hv1.x + yv1.y * hv1.y + yv1.z * hv1.z + yv1.w * hv1.w;
            ao0 += yv0.x * ov0.x + yv0.y * ov0.y + yv0.z * ov0.z + yv0.w * ov0.w;
            ao1 += yv1.x * ov1.x + yv1.y * ov1.y + yv1.z * ov1.z + yv1.w * ov1.w;
        }
        Eh[idx] = __builtin_amdgcn_exp2f((ah0 + ah1) * C2L2E);
        Eo[idx] = __builtin_amdgcn_exp2f((ao0 + ao1) * C2L2E);
    }
}

// ---------------------------------------------------------------------------
// Kernel 2: block = 8 waves = 16 queries of one batch bb (512 threads).
// __launch_bounds__(512,4): 4 waves/EU -> VGPR<=128 -> 2 blocks/CU.
// eh0 (query r0's Eh row) + w2 + vsum in SGPRs (~96, r3-proven); eh1 in VGPR.
// Eo tile staged in LDS, XOR-swizzled 16B chunks (conflict-free).
// Inner element: d=fma(eh,eo,1); rcp(d); fma(w2,.,acc) — 2 VALU + 1 trans.
// ctx-phase y loads: one base pointer + compile-time immediate offsets.
// ---------------------------------------------------------------------------
__global__ void __launch_bounds__(512, 4) k_att(
        const float* __restrict__ y,
        const float* __restrict__ Eh,
        const float* __restrict__ Eo,
        const float* __restrict__ V,
        const float* __restrict__ W_out,
        const float* __restrict__ b_out,
        float* __restrict__ out) {
    __shared__ float eo_swz[T_ * H_];      // 32 KB
    __shared__ float att_t[8][2][T_];      // 16 KB, transposed index
    __shared__ float ctx_lds[8][2][H_];    // 2 KB

    const int t    = threadIdx.x;
    const int w    = __builtin_amdgcn_readfirstlane(t >> 6);  // wave 0..7
    const int lane = t & 63;
    const int r0   = blockIdx.x * 16 + 2 * w;   // query rows r0, r0+1
    const int r1   = r0 + 1;
    const int bb   = blockIdx.x >> 4;           // batch (16 queries/block)

    // ---- stage Eo tile (swizzled), all 512 threads ----
    {
        const float4* eg = reinterpret_cast<const float4*>(Eo + bb * T_ * H_);
        float4 tmp[4];
        #pragma unroll
        for (int n = 0; n < 4; ++n) tmp[n] = eg[n * 512 + t];
        #pragma unroll
        for (int n = 0; n < 4; ++n) {
            int c = n * 512 + t;
            int j = c >> 3, p = c & 7;
            *reinterpret_cast<float4*>(&eo_swz[j * H_ + (((p ^ j) & 7) << 2)]) = tmp[n];
        }
    }
    __syncthreads();

    // ---- preamble: eh0 -> SGPR, eh1 -> VGPR, w2/vsum -> SGPR ----
    float eh0[H_];   // rfl'd -> SGPR
    float eh1[H_];   // VGPR
    float w2[H_];    // rfl'd -> SGPR
    float vsum = 0.f;
    {
        const float4* h04 = reinterpret_cast<const float4*>(Eh + r0 * H_);
        const float4* h14 = reinterpret_cast<const float4*>(Eh + r1 * H_);
        const float4* V4  = reinterpret_cast<const float4*>(V);
        #pragma unroll
        for (int p = 0; p < 8; ++p) {
            float4 a = h04[p], b = h14[p], v = V4[p];
            eh0[4 * p + 0] = rfl(a.x); eh0[4 * p + 1] = rfl(a.y);
            eh0[4 * p + 2] = rfl(a.z); eh0[4 * p + 3] = rfl(a.w);
            eh1[4 * p + 0] = b.x; eh1[4 * p + 1] = b.y;
            eh1[4 * p + 2] = b.z; eh1[4 * p + 3] = b.w;
            w2[4 * p + 0] = rfl(v.x * -2.0f); w2[4 * p + 1] = rfl(v.y * -2.0f);
            w2[4 * p + 2] = rfl(v.z * -2.0f); w2[4 * p + 3] = rfl(v.w * -2.0f);
            vsum += v.x + v.y + v.z + v.w;
        }
        vsum = rfl(vsum);
    }

    // ---- e for 4 j's per lane, both queries; Eo rows from LDS ----
    float E0[4], E1[4];
    #pragma unroll
    for (int q = 0; q < 4; ++q) {
        const int j  = lane + 64 * q;
        const int jb = j * H_;
        const int jx = (j & 7) << 2;
        float4 ev[8];
        #pragma unroll
        for (int p = 0; p < 8; ++p)
            ev[p] = *reinterpret_cast<const float4*>(&eo_swz[jb + ((p << 2) ^ jx)]);
        float a00 = 0.f, a01 = 0.f, a02 = 0.f, a03 = 0.f;
        float a10 = 0.f, a11 = 0.f, a12 = 0.f, a13 = 0.f;
        #pragma unroll
        for (int p = 0; p < 8; ++p) {
            const int k = 4 * p;
            float d;
            d = fmaf(eh0[k + 0], ev[p].x, 1.0f);
            a00 = fmaf(w2[k + 0], __builtin_amdgcn_rcpf(d), a00);
            d = fmaf(eh1[k + 0], ev[p].x, 1.0f);
            a10 = fmaf(w2[k + 0], __builtin_amdgcn_rcpf(d), a10);
            d = fmaf(eh0[k + 1], ev[p].y, 1.0f);
            a01 = fmaf(w2[k + 1], __builtin_amdgcn_rcpf(d), a01);
            d = fmaf(eh1[k + 1], ev[p].y, 1.0f);
            a11 = fmaf(w2[k + 1], __builtin_amdgcn_rcpf(d), a11);
            d = fmaf(eh0[k + 2], ev[p].z, 1.0f);
            a02 = fmaf(w2[k + 2], __builtin_amdgcn_rcpf(d), a02);
            d = fmaf(eh1[k + 2], ev[p].z, 1.0f);
            a12 = fmaf(w2[k + 2], __builtin_amdgcn_rcpf(d), a12);
            d = fmaf(eh0[k + 3], ev[p].w, 1.0f);
            a03 = fmaf(w2[k + 3], __builtin_amdgcn_rcpf(d), a03);
            d = fmaf(eh1[k + 3], ev[p].w, 1.0f);
            a13 = fmaf(w2[k + 3], __builtin_amdgcn_rcpf(d), a13);
        }
        E0[q] = ((a00 + a01) + (a02 + a03)) + vsum;
        E1[q] = ((a10 + a11) + (a12 + a13)) + vsum;
    }

    // ---- wave-local softmax (no barriers), per query ----
    float m0 = fmaxf(fmaxf(E0[0], E0[1]), fmaxf(E0[2], E0[3]));
    float m1 = fmaxf(fmaxf(E1[0], E1[1]), fmaxf(E1[2], E1[3]));
    #pragma unroll
    for (int off = 1; off < 64; off <<= 1) {
        m0 = fmaxf(m0, __shfl_xor(m0, off));
        m1 = fmaxf(m1, __shfl_xor(m1, off));
    }
    float s0 = 0.f, s1 = 0.f;
    #pragma unroll
    for (int q = 0; q < 4; ++q) {
        s0 += __builtin_amdgcn_exp2f((E0[q] - m0) * L2E);
        s1 += __builtin_amdgcn_exp2f((E1[q] - m1) * L2E);
    }
    #pragma unroll
    for (int off = 1; off < 64; off <<= 1) {
        s0 += __shfl_xor(s0, off);
        s1 += __shfl_xor(s1, off);
    }
    const float lse0 = m0 + __builtin_amdgcn_logf(s0) * LN2;
    const float lse1 = m1 + __builtin_amdgcn_logf(s1) * LN2;

    // transposed store: att_t[.][.][ (j&31)*8 + (j>>5) ]
    #pragma unroll
    for (int q = 0; q < 4; ++q) {
        const int j = lane + 64 * q;
        const int ti = (j & 31) * 8 + (j >> 5);
        att_t[w][0][ti] = E0[q] - lse0;
        att_t[w][1][ti] = E1[q] - lse1;
    }
    // same-wave LDS produce->consume: ordered by lgkmcnt, no barrier needed

    // ---- context: lane = (channel-group hg 0..7) x (jslice js 0..7),
    //      y rows from global via ONE base + immediate offsets ----
    {
        const int hg = lane & 7;
        const int js = lane >> 3;
        const float4* yb = reinterpret_cast<const float4*>(
            y + bb * T_ * H_ + (js * 32) * H_ + hg * 4);
        float4 c0 = {0, 0, 0, 0}, c1 = {0, 0, 0, 0};
        #pragma unroll
        for (int n = 0; n < 32; ++n) {
            float4 yv = yb[n * (H_ / 4)];          // imm offset n*128B
            float a0 = att_t[w][0][n * 8 + js];
            float a1 = att_t[w][1][n * 8 + js];
            c0.x = fmaf(a0, yv.x, c0.x); c0.y = fmaf(a0, yv.y, c0.y);
            c0.z = fmaf(a0, yv.z, c0.z); c0.w = fmaf(a0, yv.w, c0.w);
            c1.x = fmaf(a1, yv.x, c1.x); c1.y = fmaf(a1, yv.y, c1.y);
            c1.z = fmaf(a1, yv.z, c1.z); c1.w = fmaf(a1, yv.w, c1.w);
        }
        // reduce over js axis (lane bits 3,4,5)
        #pragma unroll
        for (int off = 8; off < 64; off <<= 1) {
            c0.x += __shfl_xor(c0.x, off); c0.y += __shfl_xor(c0.y, off);
            c0.z += __shfl_xor(c0.z, off); c0.w += __shfl_xor(c0.w, off);
            c1.x += __shfl_xor(c1.x, off); c1.y += __shfl_xor(c1.y, off);
            c1.z += __shfl_xor(c1.z, off); c1.w += __shfl_xor(c1.w, off);
        }
        if (js == 0) {
            *reinterpret_cast<float4*>(&ctx_lds[w][0][4 * hg]) = c0;
            *reinterpret_cast<float4*>(&ctx_lds[w][1][4 * hg]) = c1;
        }
    }

    // ---- output projection: 2 channels/lane x 2 queries, W_out shared ----
    float4 cv0[8], cv1[8];
    #pragma unroll
    for (int p = 0; p < 8; ++p) {
        cv0[p] = *reinterpret_cast<const float4*>(&ctx_lds[w][0][4 * p]);
        cv1[p] = *reinterpret_cast<const float4*>(&ctx_lds[w][1][4 * p]);
    }
    #pragma unroll
    for (int ho = 0; ho < 2; ++ho) {
        const int oc = lane + 64 * ho;
        const float4* w4 = reinterpret_cast<const float4*>(W_out + oc * H_);
        float b  = b_out[oc];
        float p0 = 0.f, p0b = 0.f, p1 = 0.f, p1b = 0.f;
        #pragma unroll
        for (int p = 0; p < 8; p += 2) {
            float4 wv0 = w4[p], wv1 = w4[p + 1];
            p0  += wv0.x * cv0[p].x + wv0.y * cv0[p].y + wv0.z * cv0[p].z + wv0.w * cv0[p].w;
            p0b += wv1.x * cv0[p+1].x + wv1.y * cv0[p+1].y + wv1.z * cv0[p+1].z + wv1.w * cv0[p+1].w;
            p1  += wv0.x * cv1[p].x + wv0.y * cv1[p].y + wv0.z * cv1[p].z + wv0.w * cv1[p].w;
            p1b += wv1.x * cv1[p+1].x + wv1.y * cv1[p+1].y + wv1.z * cv1[p+1].z + wv1.w * cv1[p+1].w;
        }
        out[r0 * NOUT_ + oc] = b + p0 + p0b;
        out[r1 * NOUT_ + oc] = b + p1 + p1b;
    }
}

// ---------------------------------------------------------------------------
extern "C" void kernel_launch(void* const* d_in, const int* in_sizes, int n_in,
                              void* d_out, int out_size, void* d_ws, size_t ws_size,
                              hipStream_t stream) {
    const float* x     = (const float*)d_in[0];
    const float* W_in  = (const float*)d_in[1];
    const float* b_in  = (const float*)d_in[2];
    const float* W_h   = (const float*)d_in[3];
    const float* W_o   = (const float*)d_in[4];
    const float* V     = (const float*)d_in[5];
    const float* W_out = (const float*)d_in[6];
    const float* b_out = (const float*)d_in[7];
    float* out = (float*)d_out;

    // workspace layout: y | Eh | Eo  (each R_*H_ floats = 1 MB)
    float* y  = (float*)d_ws;
    float* Eh = y + R_ * H_;
    float* Eo = Eh + R_ * H_;

    k_yho<<<R_ / 8, 256, 0, stream>>>(x, W_in, b_in, W_h, W_o, y, Eh, Eo);
    k_att<<<R_ / 16, 512, 0, stream>>>(y, Eh, Eo, V, W_out, b_out, out);
}

// Round 10
// 47.766 us; speedup vs baseline: 2.5653x; 1.0687x over previous
//
#include <hip/hip_runtime.h>
#include <hip/hip_bf16.h>

#define B_ 32
#define T_ 256
#define NIN_ 128
#define H_ 32
#define NOUT_ 128
#define R_ (B_ * T_)   // 8192 rows

#define C2L2E 2.88539008177792681472f   // 2*log2(e)
#define L2E   1.44269504088896341f
#define LN2   0.69314718055994531f

__device__ __forceinline__ float rfl(float x) {
    return __uint_as_float(__builtin_amdgcn_readfirstlane(__float_as_uint(x)));
}

// ---------------------------------------------------------------------------
// Kernel 1 (fused): per block = 8 rows x 32 h (256 threads).
// x rows staged cooperatively in LDS (ONE float4 load/thread, was 32/thread:
// kills the 32x redundant x traffic, ~128MB -> 4MB).
//   y = x @ W_in^T + b_in ; Eh = exp2(c*y@W_h^T) ; Eo = exp2(c*y@W_o^T)
// ---------------------------------------------------------------------------
__global__ void __launch_bounds__(256) k_yho(
        const float* __restrict__ x,
        const float* __restrict__ W_in,
        const float* __restrict__ b_in,
        const float* __restrict__ W_h,
        const float* __restrict__ W_o,
        float* __restrict__ y,
        float* __restrict__ Eh,
        float* __restrict__ Eo) {
    __shared__ float xs[8][NIN_];   // 4 KB
    __shared__ float ys[8][H_];     // 1 KB
    const int t   = threadIdx.x;
    const int r   = t >> 5;              // local row 0..7
    const int hh  = t & 31;
    const int row = blockIdx.x * 8 + r;
    const int idx = row * H_ + hh;

    // ---- stage 8 x-rows: thread t loads float4 chunk t (row t>>5, chunk t&31)
    reinterpret_cast<float4*>(&xs[0][0])[t] =
        reinterpret_cast<const float4*>(x + (blockIdx.x * 8) * NIN_)[t];
    __syncthreads();

    // ---- y = x @ W_in^T + b_in  (x row from LDS broadcast) ----
    {
        const float4* xl = reinterpret_cast<const float4*>(&xs[r][0]);
        const float4* w4 = reinterpret_cast<const float4*>(W_in + hh * NIN_);
        float a0 = b_in[hh], a1 = 0.f;
        #pragma unroll
        for (int k = 0; k < NIN_ / 8; ++k) {
            float4 xv0 = xl[2 * k],     wv0 = w4[2 * k];
            float4 xv1 = xl[2 * k + 1], wv1 = w4[2 * k + 1];
            a0 += xv0.x * wv0.x + xv0.y * wv0.y + xv0.z * wv0.z + xv0.w * wv0.w;
            a1 += xv1.x * wv1.x + xv1.y * wv1.y + xv1.z * wv1.z + xv1.w * wv1.w;
        }
        float acc = a0 + a1;
        ys[r][hh] = acc;
        y[idx] = acc;
    }
    __syncthreads();

    // ---- h/o projections from LDS-staged y row ----
    {
        const float4* y4  = reinterpret_cast<const float4*>(&ys[r][0]);
        const float4* wh4 = reinterpret_cast<const float4*>(W_h + hh * H_);
        const float4* wo4 = reinterpret_cast<const float4*>(W_o + hh * H_);
        float ah0 = 0.f, ah1 = 0.f, ao0 = 0.f, ao1 = 0.f;
        #pragma unroll
        for (int k = 0; k < H_ / 8; ++k) {
            float4 yv0 = y4[2 * k],     hv0 = wh4[2 * k],     ov0 = wo4[2 * k];
            float4 yv1 = y4[2 * k + 1], hv1 = wh4[2 * k + 1], ov1 = wo4[2 * k + 1];
            ah0 += yv0.x * hv0.x + yv0.y * hv0.y + yv0.z * hv0.z + yv0.w * hv0.w;
            ah1 += yv1.x * hv1.x + yv1.y * hv1.y + yv1.z * hv1.z + yv1.w * hv1.w;
            ao0 += yv0.x * ov0.x + yv0.y * ov0.y + yv0.z * ov0.z + yv0.w * ov0.w;
            ao1 += yv1.x * ov1.x + yv1.y * ov1.y + yv1.z * ov1.z + yv1.w * ov1.w;
        }
        Eh[idx] = __builtin_amdgcn_exp2f((ah0 + ah1) * C2L2E);
        Eo[idx] = __builtin_amdgcn_exp2f((ao0 + ao1) * C2L2E);
    }
}

// ---------------------------------------------------------------------------
// Kernel 2: UNCHANGED from round 9 (attribution experiment).
// block = 8 waves = 16 queries of one batch bb (512 threads), (512,4) bound.
// ---------------------------------------------------------------------------
__global__ void __launch_bounds__(512, 4) k_att(
        const float* __restrict__ y,
        const float* __restrict__ Eh,
        const float* __restrict__ Eo,
        const float* __restrict__ V,
        const float* __restrict__ W_out,
        const float* __restrict__ b_out,
        float* __restrict__ out) {
    __shared__ float eo_swz[T_ * H_];      // 32 KB
    __shared__ float att_t[8][2][T_];      // 16 KB, transposed index
    __shared__ float ctx_lds[8][2][H_];    // 2 KB

    const int t    = threadIdx.x;
    const int w    = __builtin_amdgcn_readfirstlane(t >> 6);  // wave 0..7
    const int lane = t & 63;
    const int r0   = blockIdx.x * 16 + 2 * w;   // query rows r0, r0+1
    const int r1   = r0 + 1;
    const int bb   = blockIdx.x >> 4;           // batch (16 queries/block)

    // ---- stage Eo tile (swizzled), all 512 threads ----
    {
        const float4* eg = reinterpret_cast<const float4*>(Eo + bb * T_ * H_);
        float4 tmp[4];
        #pragma unroll
        for (int n = 0; n < 4; ++n) tmp[n] = eg[n * 512 + t];
        #pragma unroll
        for (int n = 0; n < 4; ++n) {
            int c = n * 512 + t;
            int j = c >> 3, p = c & 7;
            *reinterpret_cast<float4*>(&eo_swz[j * H_ + (((p ^ j) & 7) << 2)]) = tmp[n];
        }
    }
    __syncthreads();

    // ---- preamble: eh0 -> SGPR, eh1 -> VGPR, w2/vsum -> SGPR ----
    float eh0[H_];   // rfl'd -> SGPR
    float eh1[H_];   // VGPR
    float w2[H_];    // rfl'd -> SGPR
    float vsum = 0.f;
    {
        const float4* h04 = reinterpret_cast<const float4*>(Eh + r0 * H_);
        const float4* h14 = reinterpret_cast<const float4*>(Eh + r1 * H_);
        const float4* V4  = reinterpret_cast<const float4*>(V);
        #pragma unroll
        for (int p = 0; p < 8; ++p) {
            float4 a = h04[p], b = h14[p], v = V4[p];
            eh0[4 * p + 0] = rfl(a.x); eh0[4 * p + 1] = rfl(a.y);
            eh0[4 * p + 2] = rfl(a.z); eh0[4 * p + 3] = rfl(a.w);
            eh1[4 * p + 0] = b.x; eh1[4 * p + 1] = b.y;
            eh1[4 * p + 2] = b.z; eh1[4 * p + 3] = b.w;
            w2[4 * p + 0] = rfl(v.x * -2.0f); w2[4 * p + 1] = rfl(v.y * -2.0f);
            w2[4 * p + 2] = rfl(v.z * -2.0f); w2[4 * p + 3] = rfl(v.w * -2.0f);
            vsum += v.x + v.y + v.z + v.w;
        }
        vsum = rfl(vsum);
    }

    // ---- e for 4 j's per lane, both queries; Eo rows from LDS ----
    float E0[4], E1[4];
    #pragma unroll
    for (int q = 0; q < 4; ++q) {
        const int j  = lane + 64 * q;
        const int jb = j * H_;
        const int jx = (j & 7) << 2;
        float4 ev[8];
        #pragma unroll
        for (int p = 0; p < 8; ++p)
            ev[p] = *reinterpret_cast<const float4*>(&eo_swz[jb + ((p << 2) ^ jx)]);
        float a00 = 0.f, a01 = 0.f, a02 = 0.f, a03 = 0.f;
        float a10 = 0.f, a11 = 0.f, a12 = 0.f, a13 = 0.f;
        #pragma unroll
        for (int p = 0; p < 8; ++p) {
            const int k = 4 * p;
            float d;
            d = fmaf(eh0[k + 0], ev[p].x, 1.0f);
            a00 = fmaf(w2[k + 0], __builtin_amdgcn_rcpf(d), a00);
            d = fmaf(eh1[k + 0], ev[p].x, 1.0f);
            a10 = fmaf(w2[k + 0], __builtin_amdgcn_rcpf(d), a10);
            d = fmaf(eh0[k + 1], ev[p].y, 1.0f);
            a01 = fmaf(w2[k + 1], __builtin_amdgcn_rcpf(d), a01);
            d = fmaf(eh1[k + 1], ev[p].y, 1.0f);
            a11 = fmaf(w2[k + 1], __builtin_amdgcn_rcpf(d), a11);
            d = fmaf(eh0[k + 2], ev[p].z, 1.0f);
            a02 = fmaf(w2[k + 2], __builtin_amdgcn_rcpf(d), a02);
            d = fmaf(eh1[k + 2], ev[p].z, 1.0f);
            a12 = fmaf(w2[k + 2], __builtin_amdgcn_rcpf(d), a12);
            d = fmaf(eh0[k + 3], ev[p].w, 1.0f);
            a03 = fmaf(w2[k + 3], __builtin_amdgcn_rcpf(d), a03);
            d = fmaf(eh1[k + 3], ev[p].w, 1.0f);
            a13 = fmaf(w2[k + 3], __builtin_amdgcn_rcpf(d), a13);
        }
        E0[q] = ((a00 + a01) + (a02 + a03)) + vsum;
        E1[q] = ((a10 + a11) + (a12 + a13)) + vsum;
    }

    // ---- wave-local softmax (no barriers), per query ----
    float m0 = fmaxf(fmaxf(E0[0], E0[1]), fmaxf(E0[2], E0[3]));
    float m1 = fmaxf(fmaxf(E1[0], E1[1]), fmaxf(E1[2], E1[3]));
    #pragma unroll
    for (int off = 1; off < 64; off <<= 1) {
        m0 = fmaxf(m0, __shfl_xor(m0, off));
        m1 = fmaxf(m1, __shfl_xor(m1, off));
    }
    float s0 = 0.f, s1 = 0.f;
    #pragma unroll
    for (int q = 0; q < 4; ++q) {
        s0 += __builtin_amdgcn_exp2f((E0[q] - m0) * L2E);
        s1 += __builtin_amdgcn_exp2f((E1[q] - m1) * L2E);
    }
    #pragma unroll
    for (int off = 1; off < 64; off <<= 1) {
        s0 += __shfl_xor(s0, off);
        s1 += __shfl_xor(s1, off);
    }
    const float lse0 = m0 + __builtin_amdgcn_logf(s0) * LN2;
    const float lse1 = m1 + __builtin_amdgcn_logf(s1) * LN2;

    // transposed store: att_t[.][.][ (j&31)*8 + (j>>5) ]
    #pragma unroll
    for (int q = 0; q < 4; ++q) {
        const int j = lane + 64 * q;
        const int ti = (j & 31) * 8 + (j >> 5);
        att_t[w][0][ti] = E0[q] - lse0;
        att_t[w][1][ti] = E1[q] - lse1;
    }
    // same-wave LDS produce->consume: ordered by lgkmcnt, no barrier needed

    // ---- context: lane = (channel-group hg 0..7) x (jslice js 0..7),
    //      y rows from global via ONE base + immediate offsets ----
    {
        const int hg = lane & 7;
        const int js = lane >> 3;
        const float4* yb = reinterpret_cast<const float4*>(
            y + bb * T_ * H_ + (js * 32) * H_ + hg * 4);
        float4 c0 = {0, 0, 0, 0}, c1 = {0, 0, 0, 0};
        #pragma unroll
        for (int n = 0; n < 32; ++n) {
            float4 yv = yb[n * (H_ / 4)];          // imm offset n*128B
            float a0 = att_t[w][0][n * 8 + js];
            float a1 = att_t[w][1][n * 8 + js];
            c0.x = fmaf(a0, yv.x, c0.x); c0.y = fmaf(a0, yv.y, c0.y);
            c0.z = fmaf(a0, yv.z, c0.z); c0.w = fmaf(a0, yv.w, c0.w);
            c1.x = fmaf(a1, yv.x, c1.x); c1.y = fmaf(a1, yv.y, c1.y);
            c1.z = fmaf(a1, yv.z, c1.z); c1.w = fmaf(a1, yv.w, c1.w);
        }
        // reduce over js axis (lane bits 3,4,5)
        #pragma unroll
        for (int off = 8; off < 64; off <<= 1) {
            c0.x += __shfl_xor(c0.x, off); c0.y += __shfl_xor(c0.y, off);
            c0.z += __shfl_xor(c0.z, off); c0.w += __shfl_xor(c0.w, off);
            c1.x += __shfl_xor(c1.x, off); c1.y += __shfl_xor(c1.y, off);
            c1.z += __shfl_xor(c1.z, off); c1.w += __shfl_xor(c1.w, off);
        }
        if (js == 0) {
            *reinterpret_cast<float4*>(&ctx_lds[w][0][4 * hg]) = c0;
            *reinterpret_cast<float4*>(&ctx_lds[w][1][4 * hg]) = c1;
        }
    }

    // ---- output projection: 2 channels/lane x 2 queries, W_out shared ----
    float4 cv0[8], cv1[8];
    #pragma unroll
    for (int p = 0; p < 8; ++p) {
        cv0[p] = *reinterpret_cast<const float4*>(&ctx_lds[w][0][4 * p]);
        cv1[p] = *reinterpret_cast<const float4*>(&ctx_lds[w][1][4 * p]);
    }
    #pragma unroll
    for (int ho = 0; ho < 2; ++ho) {
        const int oc = lane + 64 * ho;
        const float4* w4 = reinterpret_cast<const float4*>(W_out + oc * H_);
        float b  = b_out[oc];
        float p0 = 0.f, p0b = 0.f, p1 = 0.f, p1b = 0.f;
        #pragma unroll
        for (int p = 0; p < 8; p += 2) {
            float4 wv0 = w4[p], wv1 = w4[p + 1];
            p0  += wv0.x * cv0[p].x + wv0.y * cv0[p].y + wv0.z * cv0[p].z + wv0.w * cv0[p].w;
            p0b += wv1.x * cv0[p+1].x + wv1.y * cv0[p+1].y + wv1.z * cv0[p+1].z + wv1.w * cv0[p+1].w;
            p1  += wv0.x * cv1[p].x + wv0.y * cv1[p].y + wv0.z * cv1[p].z + wv0.w * cv1[p].w;
            p1b += wv1.x * cv1[p+1].x + wv1.y * cv1[p+1].y + wv1.z * cv1[p+1].z + wv1.w * cv1[p+1].w;
        }
        out[r0 * NOUT_ + oc] = b + p0 + p0b;
        out[r1 * NOUT_ + oc] = b + p1 + p1b;
    }
}

// ---------------------------------------------------------------------------
extern "C" void kernel_launch(void* const* d_in, const int* in_sizes, int n_in,
                              void* d_out, int out_size, void* d_ws, size_t ws_size,
                              hipStream_t stream) {
    const float* x     = (const float*)d_in[0];
    const float* W_in  = (const float*)d_in[1];
    const float* b_in  = (const float*)d_in[2];
    const float* W_h   = (const float*)d_in[3];
    const float* W_o   = (const float*)d_in[4];
    const float* V     = (const float*)d_in[5];
    const float* W_out = (const float*)d_in[6];
    const float* b_out = (const float*)d_in[7];
    float* out = (float*)d_out;

    // workspace layout: y | Eh | Eo  (each R_*H_ floats = 1 MB)
    float* y  = (float*)d_ws;
    float* Eh = y + R_ * H_;
    float* Eo = Eh + R_ * H_;

    k_yho<<<R_ / 8, 256, 0, stream>>>(x, W_in, b_in, W_h, W_o, y, Eh, Eo);
    k_att<<<R_ / 16, 512, 0, stream>>>(y, Eh, Eo, V, W_out, b_out, out);
}